// Round 2
// baseline (535.786 us; speedup 1.0000x reference)
//
#include <hip/hip_runtime.h>
#include <hip/hip_bf16.h>

typedef __hip_bfloat16 bf16;
typedef short bf16x8 __attribute__((ext_vector_type(8)));   // 8 bf16 = 4 VGPRs (A/B frag)
typedef float f32x4 __attribute__((ext_vector_type(4)));    // C/D frag

#define D_MODEL 1024
#define SEQ     2048
#define NHEAD   16
#define DHEAD   64
#define BATCH   2
#define MROWS   (BATCH*SEQ)   // 4096

// ---------------------------------------------------------------------------
// Dtype probe: decide whether input buffers hold fp32 or bf16.
// Real fp32 N(0,1/32^2) values: |v| in [1e-8,1e3] for ~all samples.
// bf16-packed pairs reinterpreted as fp32: exponent comes from bf16 bit
// pattern -> |v| ~ 2^100+ or subnormal -> ~0 sane. flag=1 means fp32 storage.
// ---------------------------------------------------------------------------
__global__ void probe_dtype(const void* __restrict__ w, int* __restrict__ flag) {
  __shared__ int cnt;
  const int tid = threadIdx.x;
  if (tid == 0) cnt = 0;
  __syncthreads();
  float v = ((const float*)w)[tid];
  bool sane = (v == v) && fabsf(v) < 1e3f && fabsf(v) > 1e-8f;
  if (sane) atomicAdd(&cnt, 1);
  __syncthreads();
  if (tid == 0) *flag = (cnt >= 128) ? 1 : 0;
}

// ---------------------------------------------------------------------------
// GEMM: C[M,N] = (A[M,K] @ W[N,K]^T + bias[N]) * scale, fp32 accum.
// 128x128 tile, BK=32, 4 waves (2x2), each wave 64x64 = 4x4 MFMA frags.
// A/W/bias/C may be fp32 or bf16 per runtime flag (wave-uniform branch).
// LDS colgroup-major: slot(g,r)=g*128+r, 16B/slot (verified m93/m97 pattern).
// ---------------------------------------------------------------------------
__global__ __launch_bounds__(256) void gemm_bias_bt(
    const void* __restrict__ A, const void* __restrict__ W,
    const void* __restrict__ bias, void* __restrict__ C,
    int M, int N, int K, float scale,
    const int* __restrict__ dflag, int a_dual, int c_dual)
{
  __shared__ __align__(16) bf16 As[4*128*8];
  __shared__ __align__(16) bf16 Ws[4*128*8];
  const int f   = *dflag;                 // 1 = external buffers are fp32
  const bool af32 = (a_dual != 0) && (f != 0);
  const bool wf32 = (f != 0);
  const bool cf32 = (c_dual != 0) && (f != 0);
  const int tid  = threadIdx.x;
  const int lane = tid & 63, wave = tid >> 6;
  const int wm   = wave >> 1, wn = wave & 1;
  const int quad = lane >> 4, l16 = lane & 15;
  const int row0 = blockIdx.y * 128, col0 = blockIdx.x * 128;

  const f32x4 zero = {0.f, 0.f, 0.f, 0.f};
  f32x4 acc[4][4];
  #pragma unroll
  for (int i = 0; i < 4; ++i)
    #pragma unroll
    for (int j = 0; j < 4; ++j) acc[i][j] = zero;

  for (int k0 = 0; k0 < K; k0 += 32) {
    __syncthreads();   // previous iteration's frag reads done
    #pragma unroll
    for (int t = 0; t < 2; ++t) {
      int s = t*256 + tid;
      int g = s >> 7, r = s & 127;
      size_t offA = (size_t)(row0 + r)*K + k0 + g*8;
      size_t offW = (size_t)(col0 + r)*K + k0 + g*8;
      if (af32) {
        const float* Af = (const float*)A + offA;
        float4 x0 = ((const float4*)Af)[0];
        float4 x1 = ((const float4*)Af)[1];
        union { uint4 q; bf16 h[8]; } pk;
        pk.h[0]=__float2bfloat16(x0.x); pk.h[1]=__float2bfloat16(x0.y);
        pk.h[2]=__float2bfloat16(x0.z); pk.h[3]=__float2bfloat16(x0.w);
        pk.h[4]=__float2bfloat16(x1.x); pk.h[5]=__float2bfloat16(x1.y);
        pk.h[6]=__float2bfloat16(x1.z); pk.h[7]=__float2bfloat16(x1.w);
        *(uint4*)&As[s*8] = pk.q;
      } else {
        *(uint4*)&As[s*8] = *(const uint4*)((const bf16*)A + offA);
      }
      if (wf32) {
        const float* Wf = (const float*)W + offW;
        float4 x0 = ((const float4*)Wf)[0];
        float4 x1 = ((const float4*)Wf)[1];
        union { uint4 q; bf16 h[8]; } pk;
        pk.h[0]=__float2bfloat16(x0.x); pk.h[1]=__float2bfloat16(x0.y);
        pk.h[2]=__float2bfloat16(x0.z); pk.h[3]=__float2bfloat16(x0.w);
        pk.h[4]=__float2bfloat16(x1.x); pk.h[5]=__float2bfloat16(x1.y);
        pk.h[6]=__float2bfloat16(x1.z); pk.h[7]=__float2bfloat16(x1.w);
        *(uint4*)&Ws[s*8] = pk.q;
      } else {
        *(uint4*)&Ws[s*8] = *(const uint4*)((const bf16*)W + offW);
      }
    }
    __syncthreads();
    bf16x8 af[4], wf[4];
    #pragma unroll
    for (int mt = 0; mt < 4; ++mt)
      af[mt] = *(const bf16x8*)&As[(quad*128 + wm*64 + mt*16 + l16)*8];
    #pragma unroll
    for (int nt = 0; nt < 4; ++nt)
      wf[nt] = *(const bf16x8*)&Ws[(quad*128 + wn*64 + nt*16 + l16)*8];
    #pragma unroll
    for (int mt = 0; mt < 4; ++mt)
      #pragma unroll
      for (int nt = 0; nt < 4; ++nt)
        acc[mt][nt] = __builtin_amdgcn_mfma_f32_16x16x32_bf16(af[mt], wf[nt], acc[mt][nt], 0, 0, 0);
  }

  // C/D layout: row = quad*4 + j, col = l16  (verified m89/m91)
  #pragma unroll
  for (int nt = 0; nt < 4; ++nt) {
    int c = col0 + wn*64 + nt*16 + l16;
    float bv = wf32 ? ((const float*)bias)[c] : __bfloat162float(((const bf16*)bias)[c]);
    #pragma unroll
    for (int mt = 0; mt < 4; ++mt) {
      int r = row0 + wm*64 + mt*16 + quad*4;
      #pragma unroll
      for (int j = 0; j < 4; ++j) {
        float outv = (acc[mt][nt][j] + bv) * scale;
        size_t idx = (size_t)(r + j)*N + c;
        if (cf32) ((float*)C)[idx] = outv;
        else      ((bf16*)C)[idx]  = __float2bfloat16(outv);
      }
    }
  }
}

// ---------------------------------------------------------------------------
// Flash attention: one block per (q-tile of 128, head, batch). 4 waves,
// each wave owns 32 q-rows. K/V tiles of 128 keys. d_h = 64.
// Q is pre-scaled by 1/8 (folded into Q-projection GEMM).
// Ao may alias Qp: each block stages exactly its own Qp slice to LDS before
// the k-loop and overwrites exactly that slice in the epilogue.
// ---------------------------------------------------------------------------
__global__ __launch_bounds__(256) void attn_fused(
    const bf16* __restrict__ Qp, const bf16* __restrict__ Kp,
    const bf16* __restrict__ Vp, bf16* __restrict__ Ao)
{
  __shared__ __align__(16) bf16 Qs[8*128*8];    // 16 KB
  __shared__ __align__(16) bf16 Ks[8*128*8];    // 16 KB
  __shared__ __align__(16) bf16 Vt[64*16*8];    // 16 KB  V^T, swizzled
  __shared__ __align__(16) bf16 Ps[128*16*8];   // 32 KB  P, swizzled

  const int tid  = threadIdx.x;
  const int lane = tid & 63, wave = tid >> 6;
  const int quad = lane >> 4, l16 = lane & 15;
  const int qt = blockIdx.x, h = blockIdx.y, b = blockIdx.z;
  const int q0 = qt * 128;
  const bf16* Qb = Qp + ((size_t)b*SEQ + q0)*D_MODEL + h*DHEAD;
  const bf16* Kb = Kp + (size_t)b*SEQ*D_MODEL + h*DHEAD;
  const bf16* Vb = Vp + (size_t)b*SEQ*D_MODEL + h*DHEAD;

  #pragma unroll
  for (int t = 0; t < 4; ++t) {
    int s = t*256 + tid;
    int g = s >> 7, r = s & 127;
    *(uint4*)&Qs[s*8] = *(const uint4*)(Qb + (size_t)r*D_MODEL + g*8);
  }
  __syncthreads();

  const int wq0 = wave * 32;
  const f32x4 zero = {0.f, 0.f, 0.f, 0.f};
  f32x4 acc_o[2][4];
  #pragma unroll
  for (int mt = 0; mt < 2; ++mt)
    #pragma unroll
    for (int dt = 0; dt < 4; ++dt) acc_o[mt][dt] = zero;
  float m_s[2][4], l_s[2][4];
  #pragma unroll
  for (int mt = 0; mt < 2; ++mt)
    #pragma unroll
    for (int j = 0; j < 4; ++j) { m_s[mt][j] = -1e30f; l_s[mt][j] = 0.f; }

  for (int kt = 0; kt < SEQ/128; ++kt) {
    const bf16* Kt_ = Kb + (size_t)kt*128*D_MODEL;
    const bf16* Vs_ = Vb + (size_t)kt*128*D_MODEL;
    #pragma unroll
    for (int t = 0; t < 4; ++t) {
      int s = t*256 + tid;
      int g = s >> 7, kk = s & 127;
      *(uint4*)&Ks[s*8] = *(const uint4*)(Kt_ + (size_t)kk*D_MODEL + g*8);
    }
    #pragma unroll
    for (int t = 0; t < 4; ++t) {
      int c = t*256 + tid;
      int key = c >> 3, g8 = c & 7;
      uint4 raw = *(const uint4*)(Vs_ + (size_t)key*D_MODEL + g8*8);
      const bf16* e = (const bf16*)&raw;
      int gk = key >> 3, kb_i = key & 7;
      #pragma unroll
      for (int i = 0; i < 8; ++i) {
        int n = g8*8 + i;
        int slot = n*16 + ((gk + n) & 15);
        Vt[slot*8 + kb_i] = e[i];
      }
    }
    __syncthreads();

    // ---- S = Q K^T (Q pre-scaled by 1/8) ----
    f32x4 sc[2][8];
    #pragma unroll
    for (int mt = 0; mt < 2; ++mt)
      #pragma unroll
      for (int nt = 0; nt < 8; ++nt) sc[mt][nt] = zero;
    #pragma unroll
    for (int ks = 0; ks < 2; ++ks) {
      bf16x8 qa[2], kf[8];
      #pragma unroll
      for (int mt = 0; mt < 2; ++mt)
        qa[mt] = *(const bf16x8*)&Qs[((ks*4 + quad)*128 + wq0 + mt*16 + l16)*8];
      #pragma unroll
      for (int nt = 0; nt < 8; ++nt)
        kf[nt] = *(const bf16x8*)&Ks[((ks*4 + quad)*128 + nt*16 + l16)*8];
      #pragma unroll
      for (int mt = 0; mt < 2; ++mt)
        #pragma unroll
        for (int nt = 0; nt < 8; ++nt)
          sc[mt][nt] = __builtin_amdgcn_mfma_f32_16x16x32_bf16(qa[mt], kf[nt], sc[mt][nt], 0, 0, 0);
    }

    // ---- online softmax: row = wq0 + mt*16 + quad*4 + j, cols over l16 ----
    #pragma unroll
    for (int mt = 0; mt < 2; ++mt) {
      float mnew[4], alpha[4], rs[4];
      #pragma unroll
      for (int j = 0; j < 4; ++j) {
        float mloc = sc[mt][0][j];
        #pragma unroll
        for (int nt = 1; nt < 8; ++nt) mloc = fmaxf(mloc, sc[mt][nt][j]);
        #pragma unroll
        for (int off = 8; off > 0; off >>= 1) mloc = fmaxf(mloc, __shfl_xor(mloc, off, 16));
        mnew[j]  = fmaxf(m_s[mt][j], mloc);
        alpha[j] = __expf(m_s[mt][j] - mnew[j]);
        rs[j]    = 0.f;
      }
      const int qrow = wq0 + mt*16 + quad*4;
      #pragma unroll
      for (int nt = 0; nt < 8; ++nt) {
        int key = nt*16 + l16;
        int gk = key >> 3, kb_i = key & 7;
        #pragma unroll
        for (int j = 0; j < 4; ++j) {
          float p = __expf(sc[mt][nt][j] - mnew[j]);
          rs[j] += p;
          int slot = (qrow + j)*16 + ((gk + qrow + j) & 15);
          Ps[slot*8 + kb_i] = __float2bfloat16(p);
        }
      }
      #pragma unroll
      for (int j = 0; j < 4; ++j) {
        #pragma unroll
        for (int off = 8; off > 0; off >>= 1) rs[j] += __shfl_xor(rs[j], off, 16);
        l_s[mt][j] = l_s[mt][j]*alpha[j] + rs[j];
        m_s[mt][j] = mnew[j];
      }
      #pragma unroll
      for (int dt = 0; dt < 4; ++dt)
        #pragma unroll
        for (int j = 0; j < 4; ++j)
          acc_o[mt][dt][j] *= alpha[j];
    }
    __syncthreads();

    // ---- O += P V : A from Ps (own rows), B from Vt ----
    #pragma unroll
    for (int ks2 = 0; ks2 < 4; ++ks2) {
      bf16x8 pa[2], vf[4];
      #pragma unroll
      for (int mt = 0; mt < 2; ++mt) {
        int qq = wq0 + mt*16 + l16;
        pa[mt] = *(const bf16x8*)&Ps[(qq*16 + ((ks2*4 + quad + qq) & 15))*8];
      }
      #pragma unroll
      for (int dt = 0; dt < 4; ++dt) {
        int n = dt*16 + l16;
        vf[dt] = *(const bf16x8*)&Vt[(n*16 + ((ks2*4 + quad + n) & 15))*8];
      }
      #pragma unroll
      for (int mt = 0; mt < 2; ++mt)
        #pragma unroll
        for (int dt = 0; dt < 4; ++dt)
          acc_o[mt][dt] = __builtin_amdgcn_mfma_f32_16x16x32_bf16(pa[mt], vf[dt], acc_o[mt][dt], 0, 0, 0);
    }
    __syncthreads();
  }

  bf16* Ob = Ao + ((size_t)b*SEQ + q0)*D_MODEL + h*DHEAD;
  #pragma unroll
  for (int mt = 0; mt < 2; ++mt)
    #pragma unroll
    for (int dt = 0; dt < 4; ++dt)
      #pragma unroll
      for (int j = 0; j < 4; ++j) {
        int r = wq0 + mt*16 + quad*4 + j;
        int c = dt*16 + l16;
        Ob[(size_t)r*D_MODEL + c] = __float2bfloat16(acc_o[mt][dt][j] / l_s[mt][j]);
      }
}

// ---------------------------------------------------------------------------
extern "C" void kernel_launch(void* const* d_in, const int* in_sizes, int n_in,
                              void* d_out, int out_size, void* d_ws, size_t ws_size,
                              hipStream_t stream) {
  const void* q   = d_in[0];
  const void* k   = d_in[1];
  const void* v   = d_in[2];
  const void* w_q = d_in[3];
  const void* b_q = d_in[4];
  const void* w_k = d_in[5];
  const void* b_k = d_in[6];
  const void* w_v = d_in[7];
  const void* b_v = d_in[8];
  const void* w_o = d_in[9];
  const void* b_o = d_in[10];

  const size_t nbuf = (size_t)MROWS * D_MODEL;    // 4M elements -> 8 MB bf16
  int*  flag = (int*)d_ws;
  bf16* Qp = (bf16*)((char*)d_ws + 256);          // ws[256 .. 8M+256)
  bf16* Vp = Qp + nbuf;                           // ws[8M+256 .. 16M+256)
  bf16* Kp = (bf16*)d_out;                        // d_out as scratch (>=8 MB)
  bf16* Ao = Qp;                                  // alias: safe, see attn_fused

  dim3 blk(256);
  dim3 gg(D_MODEL/128, MROWS/128);                // 8 x 32
  probe_dtype<<<1, 256, 0, stream>>>(w_q, flag);
  // Q projection with 1/sqrt(64) folded in (scales bias too — equivalent)
  gemm_bias_bt<<<gg, blk, 0, stream>>>(q, w_q, b_q, Qp, MROWS, D_MODEL, D_MODEL, 0.125f, flag, 1, 0);
  gemm_bias_bt<<<gg, blk, 0, stream>>>(k, w_k, b_k, Kp, MROWS, D_MODEL, D_MODEL, 1.0f,  flag, 1, 0);
  gemm_bias_bt<<<gg, blk, 0, stream>>>(v, w_v, b_v, Vp, MROWS, D_MODEL, D_MODEL, 1.0f,  flag, 1, 0);

  dim3 ga(SEQ/128, NHEAD, BATCH);                 // 16 x 16 x 2 = 512 blocks
  attn_fused<<<ga, blk, 0, stream>>>(Qp, Kp, Vp, Ao);

  gemm_bias_bt<<<gg, blk, 0, stream>>>(Ao, w_o, b_o, d_out, MROWS, D_MODEL, D_MODEL, 1.0f, flag, 0, 1);
}

// Round 3
// 399.478 us; speedup vs baseline: 1.3412x; 1.3412x over previous
//
#include <hip/hip_runtime.h>
#include <hip/hip_bf16.h>

typedef __hip_bfloat16 bf16;
typedef short bf16x8 __attribute__((ext_vector_type(8)));   // 8 bf16 = 4 VGPRs (A/B frag)
typedef float f32x4 __attribute__((ext_vector_type(4)));    // C/D frag

#define D_MODEL 1024
#define SEQ     2048
#define NHEAD   16
#define DHEAD   64
#define BATCH   2
#define MROWS   (BATCH*SEQ)   // 4096

// ---------------------------------------------------------------------------
// Dtype probe (kept for safety; round-2 confirmed fp32 storage).
// ---------------------------------------------------------------------------
__global__ void probe_dtype(const void* __restrict__ w, int* __restrict__ flag) {
  __shared__ int cnt;
  const int tid = threadIdx.x;
  if (tid == 0) cnt = 0;
  __syncthreads();
  float v = ((const float*)w)[tid];
  bool sane = (v == v) && fabsf(v) < 1e3f && fabsf(v) > 1e-8f;
  if (sane) atomicAdd(&cnt, 1);
  __syncthreads();
  if (tid == 0) *flag = (cnt >= 128) ? 1 : 0;
}

__device__ __forceinline__ uint4 pack8_f32(const float4 x0, const float4 x1) {
  union { uint4 q; bf16 h[8]; } pk;
  pk.h[0]=__float2bfloat16(x0.x); pk.h[1]=__float2bfloat16(x0.y);
  pk.h[2]=__float2bfloat16(x0.z); pk.h[3]=__float2bfloat16(x0.w);
  pk.h[4]=__float2bfloat16(x1.x); pk.h[5]=__float2bfloat16(x1.y);
  pk.h[6]=__float2bfloat16(x1.z); pk.h[7]=__float2bfloat16(x1.w);
  return pk.q;
}

// ---------------------------------------------------------------------------
// Fused QKV projection: grid.z in {0,1,2} selects (A,W,bias,C,scale).
// 768 blocks -> 3 blocks/CU (implicit staging/compute overlap).
// C[M,N] = (A @ W^T + bias) * scale, 128x128 tile, BK=32, fp32 accum.
// ---------------------------------------------------------------------------
__global__ __launch_bounds__(256) void gemm3_bias_bt(
    const void* A0, const void* A1, const void* A2,
    const void* W0, const void* W1, const void* W2,
    const void* B0, const void* B1, const void* B2,
    bf16* C0, bf16* C1, bf16* C2,
    const int* __restrict__ dflag)
{
  __shared__ __align__(16) bf16 As[4*128*8];
  __shared__ __align__(16) bf16 Ws[4*128*8];
  const int z = blockIdx.z;
  const void* A = (z == 0) ? A0 : (z == 1) ? A1 : A2;
  const void* W = (z == 0) ? W0 : (z == 1) ? W1 : W2;
  const void* Bv = (z == 0) ? B0 : (z == 1) ? B1 : B2;
  bf16* C = (z == 0) ? C0 : (z == 1) ? C1 : C2;
  const float scale = (z == 0) ? 0.125f : 1.0f;   // fold 1/sqrt(d_k) into Q
  const int K = D_MODEL, N = D_MODEL;
  const int f = *dflag;
  const bool is32 = (f != 0);
  const int tid  = threadIdx.x;
  const int lane = tid & 63, wave = tid >> 6;
  const int wm   = wave >> 1, wn = wave & 1;
  const int quad = lane >> 4, l16 = lane & 15;
  const int row0 = blockIdx.y * 128, col0 = blockIdx.x * 128;

  const f32x4 zero = {0.f, 0.f, 0.f, 0.f};
  f32x4 acc[4][4];
  #pragma unroll
  for (int i = 0; i < 4; ++i)
    #pragma unroll
    for (int j = 0; j < 4; ++j) acc[i][j] = zero;

  for (int k0 = 0; k0 < K; k0 += 32) {
    __syncthreads();
    #pragma unroll
    for (int t = 0; t < 2; ++t) {
      int s = t*256 + tid;
      int g = s >> 7, r = s & 127;
      size_t offA = (size_t)(row0 + r)*K + k0 + g*8;
      size_t offW = (size_t)(col0 + r)*K + k0 + g*8;
      if (is32) {
        const float* Af = (const float*)A + offA;
        *(uint4*)&As[s*8] = pack8_f32(((const float4*)Af)[0], ((const float4*)Af)[1]);
        const float* Wf = (const float*)W + offW;
        *(uint4*)&Ws[s*8] = pack8_f32(((const float4*)Wf)[0], ((const float4*)Wf)[1]);
      } else {
        *(uint4*)&As[s*8] = *(const uint4*)((const bf16*)A + offA);
        *(uint4*)&Ws[s*8] = *(const uint4*)((const bf16*)W + offW);
      }
    }
    __syncthreads();
    bf16x8 af[4], wf[4];
    #pragma unroll
    for (int mt = 0; mt < 4; ++mt)
      af[mt] = *(const bf16x8*)&As[(quad*128 + wm*64 + mt*16 + l16)*8];
    #pragma unroll
    for (int nt = 0; nt < 4; ++nt)
      wf[nt] = *(const bf16x8*)&Ws[(quad*128 + wn*64 + nt*16 + l16)*8];
    #pragma unroll
    for (int mt = 0; mt < 4; ++mt)
      #pragma unroll
      for (int nt = 0; nt < 4; ++nt)
        acc[mt][nt] = __builtin_amdgcn_mfma_f32_16x16x32_bf16(af[mt], wf[nt], acc[mt][nt], 0, 0, 0);
  }

  #pragma unroll
  for (int nt = 0; nt < 4; ++nt) {
    int c = col0 + wn*64 + nt*16 + l16;
    float bv = is32 ? ((const float*)Bv)[c] : __bfloat162float(((const bf16*)Bv)[c]);
    #pragma unroll
    for (int mt = 0; mt < 4; ++mt) {
      int r = row0 + wm*64 + mt*16 + quad*4;
      #pragma unroll
      for (int j = 0; j < 4; ++j)
        C[(size_t)(r + j)*N + c] = __float2bfloat16((acc[mt][nt][j] + bv) * scale);
    }
  }
}

// ---------------------------------------------------------------------------
// Output projection: 128x64 tile -> grid 16x32 = 512 blocks = 2/CU.
// A (attention out) is always bf16; W/bias/C follow dtype flag.
// ---------------------------------------------------------------------------
__global__ __launch_bounds__(256) void gemm_out(
    const bf16* __restrict__ A, const void* __restrict__ W,
    const void* __restrict__ Bv, void* __restrict__ C,
    const int* __restrict__ dflag)
{
  __shared__ __align__(16) bf16 As[4*128*8];   // 8 KB
  __shared__ __align__(16) bf16 Ws[4*64*8];    // 4 KB
  const int K = D_MODEL, N = D_MODEL;
  const int f = *dflag;
  const bool is32 = (f != 0);
  const int tid  = threadIdx.x;
  const int lane = tid & 63, wave = tid >> 6;
  const int wm   = wave >> 1, wn = wave & 1;
  const int quad = lane >> 4, l16 = lane & 15;
  const int row0 = blockIdx.y * 128, col0 = blockIdx.x * 64;

  const f32x4 zero = {0.f, 0.f, 0.f, 0.f};
  f32x4 acc[4][2];
  #pragma unroll
  for (int i = 0; i < 4; ++i)
    #pragma unroll
    for (int j = 0; j < 2; ++j) acc[i][j] = zero;

  for (int k0 = 0; k0 < K; k0 += 32) {
    __syncthreads();
    #pragma unroll
    for (int t = 0; t < 2; ++t) {
      int s = t*256 + tid;
      int g = s >> 7, r = s & 127;
      *(uint4*)&As[s*8] = *(const uint4*)(A + (size_t)(row0 + r)*K + k0 + g*8);
    }
    {
      int s = tid;                 // 256 slots: g = s>>6, r = s&63
      int g = s >> 6, r = s & 63;
      size_t offW = (size_t)(col0 + r)*K + k0 + g*8;
      if (is32) {
        const float* Wf = (const float*)W + offW;
        *(uint4*)&Ws[s*8] = pack8_f32(((const float4*)Wf)[0], ((const float4*)Wf)[1]);
      } else {
        *(uint4*)&Ws[s*8] = *(const uint4*)((const bf16*)W + offW);
      }
    }
    __syncthreads();
    bf16x8 af[4], wf[2];
    #pragma unroll
    for (int mt = 0; mt < 4; ++mt)
      af[mt] = *(const bf16x8*)&As[(quad*128 + wm*64 + mt*16 + l16)*8];
    #pragma unroll
    for (int nt = 0; nt < 2; ++nt)
      wf[nt] = *(const bf16x8*)&Ws[(quad*64 + wn*32 + nt*16 + l16)*8];
    #pragma unroll
    for (int mt = 0; mt < 4; ++mt)
      #pragma unroll
      for (int nt = 0; nt < 2; ++nt)
        acc[mt][nt] = __builtin_amdgcn_mfma_f32_16x16x32_bf16(af[mt], wf[nt], acc[mt][nt], 0, 0, 0);
  }

  #pragma unroll
  for (int nt = 0; nt < 2; ++nt) {
    int c = col0 + wn*32 + nt*16 + l16;
    float bv = is32 ? ((const float*)Bv)[c] : __bfloat162float(((const bf16*)Bv)[c]);
    #pragma unroll
    for (int mt = 0; mt < 4; ++mt) {
      int r = row0 + wm*64 + mt*16 + quad*4;
      #pragma unroll
      for (int j = 0; j < 4; ++j) {
        float outv = acc[mt][nt][j] + bv;
        size_t idx = (size_t)(r + j)*N + c;
        if (is32) ((float*)C)[idx] = outv;
        else      ((bf16*)C)[idx]  = __float2bfloat16(outv);
      }
    }
  }
}

// ---------------------------------------------------------------------------
// Flash attention, S^T formulation: S^T = K·Q^T so C/D gives each lane 4
// CONSECUTIVE KEYS at fixed q=l16 -> vectorized P stores (8B), 16B P loads,
// lane-uniform alpha, 2-shuffle row reductions, packed 8B epilogue stores.
// O^T = V^T·P^T. Ps: 128 rows x 256B, XOR swizzle on 8B chunks (bits 1..3;
// bit0 preserved so 16B reads stay aligned) -> conflict-free R/W.
// Vt swizzle (gk + n + (n>>3)) spreads the transpose's scalar stores across
// banks (old (gk+n) put all 16 lanes of a phase on one bank pair).
// ---------------------------------------------------------------------------
__global__ __launch_bounds__(256) void attn_fused(
    const bf16* __restrict__ Qp, const bf16* __restrict__ Kp,
    const bf16* __restrict__ Vp, bf16* __restrict__ Ao)
{
  __shared__ __align__(16) bf16 Qs[8*128*8];    // 16 KB colgroup: slot g*128+r
  __shared__ __align__(16) bf16 Ks[8*128*8];    // 16 KB
  __shared__ __align__(16) bf16 Vt[64*16*8];    // 16 KB  V^T, swizzled
  __shared__ __align__(16) bf16 Ps[128*128];    // 32 KB  P[q][key], chunk-swizzled

  const int tid  = threadIdx.x;
  const int lane = tid & 63, wave = tid >> 6;
  const int quad = lane >> 4, l16 = lane & 15;
  const int qt = blockIdx.x, h = blockIdx.y, b = blockIdx.z;
  const int q0 = qt * 128;
  const bf16* Qb = Qp + ((size_t)b*SEQ + q0)*D_MODEL + h*DHEAD;
  const bf16* Kb = Kp + (size_t)b*SEQ*D_MODEL + h*DHEAD;
  const bf16* Vb = Vp + (size_t)b*SEQ*D_MODEL + h*DHEAD;

  #pragma unroll
  for (int t = 0; t < 4; ++t) {
    int s = t*256 + tid;
    int g = s >> 7, r = s & 127;
    *(uint4*)&Qs[s*8] = *(const uint4*)(Qb + (size_t)r*D_MODEL + g*8);
  }
  __syncthreads();

  const int wq0 = wave * 32;
  const int swz = (l16 & 7) << 1;              // Ps chunk swizzle term
  const f32x4 zero = {0.f, 0.f, 0.f, 0.f};
  f32x4 acc_o[2][4];                           // [q-tile mt][d-tile dt], O^T layout
  #pragma unroll
  for (int mt = 0; mt < 2; ++mt)
    #pragma unroll
    for (int dt = 0; dt < 4; ++dt) acc_o[mt][dt] = zero;
  float m_s[2] = {-1e30f, -1e30f}, l_s[2] = {0.f, 0.f};

  for (int kt = 0; kt < SEQ/128; ++kt) {
    const bf16* Kt_ = Kb + (size_t)kt*128*D_MODEL;
    const bf16* Vs_ = Vb + (size_t)kt*128*D_MODEL;
    #pragma unroll
    for (int t = 0; t < 4; ++t) {
      int s = t*256 + tid;
      int g = s >> 7, kk = s & 127;
      *(uint4*)&Ks[s*8] = *(const uint4*)(Kt_ + (size_t)kk*D_MODEL + g*8);
    }
    #pragma unroll
    for (int t = 0; t < 4; ++t) {
      int c = t*256 + tid;
      int key = c >> 3, g8 = c & 7;
      uint4 raw = *(const uint4*)(Vs_ + (size_t)key*D_MODEL + g8*8);
      const bf16* e = (const bf16*)&raw;
      int gk = key >> 3, kb_i = key & 7;
      #pragma unroll
      for (int i = 0; i < 8; ++i) {
        int n = g8*8 + i;
        int sw = (gk + n + (n >> 3)) & 15;
        Vt[(n*16 + sw)*8 + kb_i] = e[i];
      }
    }
    __syncthreads();

    // ---- S^T = K Q^T : C/D row = key = kt2*16+quad*4+j, col = q = l16 ----
    f32x4 sc[2][8];
    #pragma unroll
    for (int mt = 0; mt < 2; ++mt)
      #pragma unroll
      for (int kt2 = 0; kt2 < 8; ++kt2) sc[mt][kt2] = zero;
    #pragma unroll
    for (int ks = 0; ks < 2; ++ks) {
      bf16x8 qa[2], kf[8];
      #pragma unroll
      for (int mt = 0; mt < 2; ++mt)
        qa[mt] = *(const bf16x8*)&Qs[((ks*4 + quad)*128 + wq0 + mt*16 + l16)*8];
      #pragma unroll
      for (int kt2 = 0; kt2 < 8; ++kt2)
        kf[kt2] = *(const bf16x8*)&Ks[((ks*4 + quad)*128 + kt2*16 + l16)*8];
      #pragma unroll
      for (int mt = 0; mt < 2; ++mt)
        #pragma unroll
        for (int kt2 = 0; kt2 < 8; ++kt2)
          sc[mt][kt2] = __builtin_amdgcn_mfma_f32_16x16x32_bf16(kf[kt2], qa[mt], sc[mt][kt2], 0, 0, 0);
    }

    // ---- online softmax; this lane owns q = wq0+mt*16+l16 (x4 quads) ----
    #pragma unroll
    for (int mt = 0; mt < 2; ++mt) {
      const int q = wq0 + mt*16 + l16;
      float vmax = -1e30f;
      #pragma unroll
      for (int kt2 = 0; kt2 < 8; ++kt2) {
        f32x4 s4 = sc[mt][kt2];
        vmax = fmaxf(vmax, fmaxf(fmaxf(s4[0], s4[1]), fmaxf(s4[2], s4[3])));
      }
      vmax = fmaxf(vmax, __shfl_xor(vmax, 16));
      vmax = fmaxf(vmax, __shfl_xor(vmax, 32));
      float mnew  = fmaxf(m_s[mt], vmax);
      float alpha = __expf(m_s[mt] - mnew);
      float rs = 0.f;
      #pragma unroll
      for (int kt2 = 0; kt2 < 8; ++kt2) {
        float p0 = __expf(sc[mt][kt2][0] - mnew);
        float p1 = __expf(sc[mt][kt2][1] - mnew);
        float p2 = __expf(sc[mt][kt2][2] - mnew);
        float p3 = __expf(sc[mt][kt2][3] - mnew);
        rs += (p0 + p1) + (p2 + p3);
        union { uint2 u; bf16 h[4]; } pk;
        pk.h[0] = __float2bfloat16(p0); pk.h[1] = __float2bfloat16(p1);
        pk.h[2] = __float2bfloat16(p2); pk.h[3] = __float2bfloat16(p3);
        int phys = (kt2*4 + quad) ^ swz;
        *(uint2*)&Ps[q*128 + phys*4] = pk.u;
      }
      rs += __shfl_xor(rs, 16);
      rs += __shfl_xor(rs, 32);
      l_s[mt] = l_s[mt]*alpha + rs;
      m_s[mt] = mnew;
      #pragma unroll
      for (int dt = 0; dt < 4; ++dt) acc_o[mt][dt] = acc_o[mt][dt] * alpha;
    }
    __syncthreads();   // Ps writes visible (conservative; per-wave rows only)

    // ---- O^T += V^T P^T : A = V^T frag, B = P^T frag (16B Ps reads) ----
    #pragma unroll
    for (int ks2 = 0; ks2 < 4; ++ks2) {
      bf16x8 vf[4], pa[2];
      #pragma unroll
      for (int dt = 0; dt < 4; ++dt) {
        int n = dt*16 + l16;
        int sw = (ks2*4 + quad + n + (n >> 3)) & 15;
        vf[dt] = *(const bf16x8*)&Vt[(n*16 + sw)*8];
      }
      int phys = (ks2*8 + quad*2) ^ swz;
      #pragma unroll
      for (int mt = 0; mt < 2; ++mt) {
        int q = wq0 + mt*16 + l16;
        pa[mt] = *(const bf16x8*)&Ps[q*128 + phys*4];
      }
      #pragma unroll
      for (int mt = 0; mt < 2; ++mt)
        #pragma unroll
        for (int dt = 0; dt < 4; ++dt)
          acc_o[mt][dt] = __builtin_amdgcn_mfma_f32_16x16x32_bf16(vf[dt], pa[mt], acc_o[mt][dt], 0, 0, 0);
    }
    __syncthreads();   // all waves done with Ks/Vt before restaging
  }

  // ---- epilogue: lane holds O[q][d..d+3], packed 8B stores ----
  bf16* Ob = Ao + ((size_t)b*SEQ + q0)*D_MODEL + h*DHEAD;
  #pragma unroll
  for (int mt = 0; mt < 2; ++mt) {
    float inv = 1.f / l_s[mt];
    int q = wq0 + mt*16 + l16;
    #pragma unroll
    for (int dt = 0; dt < 4; ++dt) {
      union { uint2 u; bf16 h[4]; } pk;
      #pragma unroll
      for (int j = 0; j < 4; ++j) pk.h[j] = __float2bfloat16(acc_o[mt][dt][j] * inv);
      *(uint2*)(Ob + (size_t)q*D_MODEL + dt*16 + quad*4) = pk.u;
    }
  }
}

// ---------------------------------------------------------------------------
extern "C" void kernel_launch(void* const* d_in, const int* in_sizes, int n_in,
                              void* d_out, int out_size, void* d_ws, size_t ws_size,
                              hipStream_t stream) {
  const void* q   = d_in[0];
  const void* k   = d_in[1];
  const void* v   = d_in[2];
  const void* w_q = d_in[3];
  const void* b_q = d_in[4];
  const void* w_k = d_in[5];
  const void* b_k = d_in[6];
  const void* w_v = d_in[7];
  const void* b_v = d_in[8];
  const void* w_o = d_in[9];
  const void* b_o = d_in[10];

  const size_t nbuf = (size_t)MROWS * D_MODEL;    // 4M elems -> 8 MB bf16
  int*  flag = (int*)d_ws;
  bf16* Qp = (bf16*)((char*)d_ws + 256);
  bf16* Vp = Qp + nbuf;
  bf16* Kp = (bf16*)d_out;                        // d_out as scratch (fp32 out => 16MB)
  bf16* Ao = Qp;                                  // alias: block-local slices only

  dim3 blk(256);
  probe_dtype<<<1, 256, 0, stream>>>(w_q, flag);

  dim3 g3(D_MODEL/128, MROWS/128, 3);             // 8 x 32 x 3 = 768 blocks
  gemm3_bias_bt<<<g3, blk, 0, stream>>>(q, k, v, w_q, w_k, w_v,
                                        b_q, b_k, b_v, Qp, Kp, Vp, flag);

  dim3 ga(SEQ/128, NHEAD, BATCH);                 // 512 blocks
  attn_fused<<<ga, blk, 0, stream>>>(Qp, Kp, Vp, Ao);

  dim3 go(D_MODEL/64, MROWS/128);                 // 16 x 32 = 512 blocks
  gemm_out<<<go, blk, 0, stream>>>(Ao, w_o, b_o, d_out, flag);
}

// Round 4
// 314.122 us; speedup vs baseline: 1.7057x; 1.2717x over previous
//
#include <hip/hip_runtime.h>
#include <hip/hip_bf16.h>

typedef __hip_bfloat16 bf16;
typedef short bf16x8 __attribute__((ext_vector_type(8)));   // 8 bf16 = 4 VGPRs
typedef float f32x4 __attribute__((ext_vector_type(4)));    // C/D frag

#define D_MODEL 1024
#define SEQ     2048
#define NHEAD   16
#define DHEAD   64
#define BATCH   2
#define MROWS   (BATCH*SEQ)   // 4096
#define LOG2E   1.4426950408889634f

// async global->LDS, 16B per lane (m97: the 517->874 TF lever)
__device__ __forceinline__ void lds_dma16(const bf16* g, bf16* l) {
  __builtin_amdgcn_global_load_lds(
      (const __attribute__((address_space(1))) void*)g,
      (__attribute__((address_space(3))) void*)l, 16, 0, 0);
}

__device__ __forceinline__ uint4 pack8_f32(const float4 x0, const float4 x1) {
  union { uint4 q; bf16 h[8]; } pk;
  pk.h[0]=__float2bfloat16(x0.x); pk.h[1]=__float2bfloat16(x0.y);
  pk.h[2]=__float2bfloat16(x0.z); pk.h[3]=__float2bfloat16(x0.w);
  pk.h[4]=__float2bfloat16(x1.x); pk.h[5]=__float2bfloat16(x1.y);
  pk.h[6]=__float2bfloat16(x1.z); pk.h[7]=__float2bfloat16(x1.w);
  return pk.q;
}

// ---------------------------------------------------------------------------
__global__ void probe_dtype(const void* __restrict__ w, int* __restrict__ flag) {
  __shared__ int cnt;
  const int tid = threadIdx.x;
  if (tid == 0) cnt = 0;
  __syncthreads();
  float v = ((const float*)w)[tid];
  bool sane = (v == v) && fabsf(v) < 1e3f && fabsf(v) > 1e-8f;
  if (sane) atomicAdd(&cnt, 1);
  __syncthreads();
  if (tid == 0) *flag = (cnt >= 128) ? 1 : 0;
}

// ---------------------------------------------------------------------------
// Convert 7 buffers fp32->bf16 (or copy if already bf16). grid (512, 7).
// z<3: q,k,v (4.19M elems); z>=3: w_q,w_k,w_v,w_o (1.05M elems).
// ---------------------------------------------------------------------------
__global__ __launch_bounds__(256) void convert7(
    const void* s0, const void* s1, const void* s2, const void* s3,
    const void* s4, const void* s5, const void* s6,
    bf16* d0, bf16* d1, bf16* d2, bf16* d3, bf16* d4, bf16* d5, bf16* d6,
    const int* __restrict__ dflag)
{
  const void* S[7] = {s0,s1,s2,s3,s4,s5,s6};
  bf16*       D[7] = {d0,d1,d2,d3,d4,d5,d6};
  const int z = blockIdx.y;
  const int n8 = (z < 3) ? (MROWS*D_MODEL/8) : (D_MODEL*D_MODEL/8);
  const bool is32 = (*dflag != 0);
  for (int i = blockIdx.x*256 + threadIdx.x; i < n8; i += 512*256) {
    if (is32) {
      float4 a = ((const float4*)S[z])[2*i];
      float4 b = ((const float4*)S[z])[2*i+1];
      ((uint4*)D[z])[i] = pack8_f32(a, b);
    } else {
      ((uint4*)D[z])[i] = ((const uint4*)S[z])[i];
    }
  }
}

// ---------------------------------------------------------------------------
// PATH A: pure-bf16 fused QKV GEMM with global_load_lds staging.
// C = (A @ W^T + bias)*scale; 128x128 tile, BK=32; grid (8,32,3)=768 blocks.
// ---------------------------------------------------------------------------
__global__ __launch_bounds__(256) void gemm3_dma(
    const bf16* A0, const bf16* A1, const bf16* A2,
    const bf16* W0, const bf16* W1, const bf16* W2,
    const void* B0, const void* B1, const void* B2,
    bf16* C0, bf16* C1, bf16* C2, const int* __restrict__ dflag)
{
  __shared__ __align__(16) bf16 As[4*128*8];
  __shared__ __align__(16) bf16 Ws[4*128*8];
  const int z = blockIdx.z;
  const bf16* A = (z == 0) ? A0 : (z == 1) ? A1 : A2;
  const bf16* W = (z == 0) ? W0 : (z == 1) ? W1 : W2;
  const void* Bv = (z == 0) ? B0 : (z == 1) ? B1 : B2;
  bf16* C = (z == 0) ? C0 : (z == 1) ? C1 : C2;
  const float scale = (z == 0) ? 0.125f*LOG2E : 1.0f;  // Q: 1/sqrt(d) * log2e
  const int K = D_MODEL, N = D_MODEL;
  const bool is32 = (*dflag != 0);
  const int tid  = threadIdx.x;
  const int lane = tid & 63, wave = tid >> 6;
  const int wm   = wave >> 1, wn = wave & 1;
  const int quad = lane >> 4, l16 = lane & 15;
  const int row0 = blockIdx.y * 128, col0 = blockIdx.x * 128;

  const f32x4 zero = {0.f, 0.f, 0.f, 0.f};
  f32x4 acc[4][4];
  #pragma unroll
  for (int i = 0; i < 4; ++i)
    #pragma unroll
    for (int j = 0; j < 4; ++j) acc[i][j] = zero;

  for (int k0 = 0; k0 < K; k0 += 32) {
    __syncthreads();
    #pragma unroll
    for (int t = 0; t < 2; ++t) {
      int s = t*256 + tid;
      int g = s >> 7, r = s & 127;
      lds_dma16(A + (size_t)(row0 + r)*K + k0 + g*8, &As[s*8]);
      lds_dma16(W + (size_t)(col0 + r)*K + k0 + g*8, &Ws[s*8]);
    }
    __syncthreads();
    bf16x8 af[4], wf[4];
    #pragma unroll
    for (int mt = 0; mt < 4; ++mt)
      af[mt] = *(const bf16x8*)&As[(quad*128 + wm*64 + mt*16 + l16)*8];
    #pragma unroll
    for (int nt = 0; nt < 4; ++nt)
      wf[nt] = *(const bf16x8*)&Ws[(quad*128 + wn*64 + nt*16 + l16)*8];
    #pragma unroll
    for (int mt = 0; mt < 4; ++mt)
      #pragma unroll
      for (int nt = 0; nt < 4; ++nt)
        acc[mt][nt] = __builtin_amdgcn_mfma_f32_16x16x32_bf16(af[mt], wf[nt], acc[mt][nt], 0, 0, 0);
  }

  #pragma unroll
  for (int nt = 0; nt < 4; ++nt) {
    int c = col0 + wn*64 + nt*16 + l16;
    float bv = is32 ? ((const float*)Bv)[c] : __bfloat162float(((const bf16*)Bv)[c]);
    #pragma unroll
    for (int mt = 0; mt < 4; ++mt) {
      int r = row0 + wm*64 + mt*16 + quad*4;
      #pragma unroll
      for (int j = 0; j < 4; ++j)
        C[(size_t)(r + j)*N + c] = __float2bfloat16((acc[mt][nt][j] + bv) * scale);
    }
  }
}

// ---------------------------------------------------------------------------
// PATH A: output projection, bf16 A & W via DMA; 128x64 tile; 512 blocks.
// ---------------------------------------------------------------------------
__global__ __launch_bounds__(256) void gemm_out_dma(
    const bf16* __restrict__ A, const bf16* __restrict__ W,
    const void* __restrict__ Bv, void* __restrict__ C,
    const int* __restrict__ dflag)
{
  __shared__ __align__(16) bf16 As[4*128*8];   // 8 KB
  __shared__ __align__(16) bf16 Ws[4*64*8];    // 4 KB
  const int K = D_MODEL, N = D_MODEL;
  const bool is32 = (*dflag != 0);
  const int tid  = threadIdx.x;
  const int lane = tid & 63, wave = tid >> 6;
  const int wm   = wave >> 1, wn = wave & 1;
  const int quad = lane >> 4, l16 = lane & 15;
  const int row0 = blockIdx.y * 128, col0 = blockIdx.x * 64;

  const f32x4 zero = {0.f, 0.f, 0.f, 0.f};
  f32x4 acc[4][2];
  #pragma unroll
  for (int i = 0; i < 4; ++i)
    #pragma unroll
    for (int j = 0; j < 2; ++j) acc[i][j] = zero;

  for (int k0 = 0; k0 < K; k0 += 32) {
    __syncthreads();
    #pragma unroll
    for (int t = 0; t < 2; ++t) {
      int s = t*256 + tid;
      int g = s >> 7, r = s & 127;
      lds_dma16(A + (size_t)(row0 + r)*K + k0 + g*8, &As[s*8]);
    }
    {
      int g = tid >> 6, r = tid & 63;
      lds_dma16(W + (size_t)(col0 + r)*K + k0 + g*8, &Ws[tid*8]);
    }
    __syncthreads();
    bf16x8 af[4], wf[2];
    #pragma unroll
    for (int mt = 0; mt < 4; ++mt)
      af[mt] = *(const bf16x8*)&As[(quad*128 + wm*64 + mt*16 + l16)*8];
    #pragma unroll
    for (int nt = 0; nt < 2; ++nt)
      wf[nt] = *(const bf16x8*)&Ws[(quad*64 + wn*32 + nt*16 + l16)*8];
    #pragma unroll
    for (int mt = 0; mt < 4; ++mt)
      #pragma unroll
      for (int nt = 0; nt < 2; ++nt)
        acc[mt][nt] = __builtin_amdgcn_mfma_f32_16x16x32_bf16(af[mt], wf[nt], acc[mt][nt], 0, 0, 0);
  }

  #pragma unroll
  for (int nt = 0; nt < 2; ++nt) {
    int c = col0 + wn*32 + nt*16 + l16;
    float bv = is32 ? ((const float*)Bv)[c] : __bfloat162float(((const bf16*)Bv)[c]);
    #pragma unroll
    for (int mt = 0; mt < 4; ++mt) {
      int r = row0 + wm*64 + mt*16 + quad*4;
      #pragma unroll
      for (int j = 0; j < 4; ++j) {
        float outv = acc[mt][nt][j] + bv;
        size_t idx = (size_t)(r + j)*N + c;
        if (is32) ((float*)C)[idx] = outv;
        else      ((bf16*)C)[idx]  = __float2bfloat16(outv);
      }
    }
  }
}

// ---------------------------------------------------------------------------
// PATH B fallback (ws too small): round-3 fused-convert GEMMs.
// ---------------------------------------------------------------------------
__global__ __launch_bounds__(256) void gemm3_fused(
    const void* A0, const void* A1, const void* A2,
    const void* W0, const void* W1, const void* W2,
    const void* B0, const void* B1, const void* B2,
    bf16* C0, bf16* C1, bf16* C2, const int* __restrict__ dflag)
{
  __shared__ __align__(16) bf16 As[4*128*8];
  __shared__ __align__(16) bf16 Ws[4*128*8];
  const int z = blockIdx.z;
  const void* A = (z == 0) ? A0 : (z == 1) ? A1 : A2;
  const void* W = (z == 0) ? W0 : (z == 1) ? W1 : W2;
  const void* Bv = (z == 0) ? B0 : (z == 1) ? B1 : B2;
  bf16* C = (z == 0) ? C0 : (z == 1) ? C1 : C2;
  const float scale = (z == 0) ? 0.125f*LOG2E : 1.0f;
  const int K = D_MODEL, N = D_MODEL;
  const bool is32 = (*dflag != 0);
  const int tid  = threadIdx.x;
  const int lane = tid & 63, wave = tid >> 6;
  const int wm   = wave >> 1, wn = wave & 1;
  const int quad = lane >> 4, l16 = lane & 15;
  const int row0 = blockIdx.y * 128, col0 = blockIdx.x * 128;

  const f32x4 zero = {0.f, 0.f, 0.f, 0.f};
  f32x4 acc[4][4];
  #pragma unroll
  for (int i = 0; i < 4; ++i)
    #pragma unroll
    for (int j = 0; j < 4; ++j) acc[i][j] = zero;

  for (int k0 = 0; k0 < K; k0 += 32) {
    __syncthreads();
    #pragma unroll
    for (int t = 0; t < 2; ++t) {
      int s = t*256 + tid;
      int g = s >> 7, r = s & 127;
      size_t offA = (size_t)(row0 + r)*K + k0 + g*8;
      size_t offW = (size_t)(col0 + r)*K + k0 + g*8;
      if (is32) {
        const float* Af = (const float*)A + offA;
        *(uint4*)&As[s*8] = pack8_f32(((const float4*)Af)[0], ((const float4*)Af)[1]);
        const float* Wf = (const float*)W + offW;
        *(uint4*)&Ws[s*8] = pack8_f32(((const float4*)Wf)[0], ((const float4*)Wf)[1]);
      } else {
        *(uint4*)&As[s*8] = *(const uint4*)((const bf16*)A + offA);
        *(uint4*)&Ws[s*8] = *(const uint4*)((const bf16*)W + offW);
      }
    }
    __syncthreads();
    bf16x8 af[4], wf[4];
    #pragma unroll
    for (int mt = 0; mt < 4; ++mt)
      af[mt] = *(const bf16x8*)&As[(quad*128 + wm*64 + mt*16 + l16)*8];
    #pragma unroll
    for (int nt = 0; nt < 4; ++nt)
      wf[nt] = *(const bf16x8*)&Ws[(quad*128 + wn*64 + nt*16 + l16)*8];
    #pragma unroll
    for (int mt = 0; mt < 4; ++mt)
      #pragma unroll
      for (int nt = 0; nt < 4; ++nt)
        acc[mt][nt] = __builtin_amdgcn_mfma_f32_16x16x32_bf16(af[mt], wf[nt], acc[mt][nt], 0, 0, 0);
  }
  #pragma unroll
  for (int nt = 0; nt < 4; ++nt) {
    int c = col0 + wn*64 + nt*16 + l16;
    float bv = is32 ? ((const float*)Bv)[c] : __bfloat162float(((const bf16*)Bv)[c]);
    #pragma unroll
    for (int mt = 0; mt < 4; ++mt) {
      int r = row0 + wm*64 + mt*16 + quad*4;
      #pragma unroll
      for (int j = 0; j < 4; ++j)
        C[(size_t)(r + j)*N + c] = __float2bfloat16((acc[mt][nt][j] + bv) * scale);
    }
  }
}

__global__ __launch_bounds__(256) void gemm_out_fused(
    const bf16* __restrict__ A, const void* __restrict__ W,
    const void* __restrict__ Bv, void* __restrict__ C,
    const int* __restrict__ dflag)
{
  __shared__ __align__(16) bf16 As[4*128*8];
  __shared__ __align__(16) bf16 Ws[4*64*8];
  const int K = D_MODEL, N = D_MODEL;
  const bool is32 = (*dflag != 0);
  const int tid  = threadIdx.x;
  const int lane = tid & 63, wave = tid >> 6;
  const int wm   = wave >> 1, wn = wave & 1;
  const int quad = lane >> 4, l16 = lane & 15;
  const int row0 = blockIdx.y * 128, col0 = blockIdx.x * 64;

  const f32x4 zero = {0.f, 0.f, 0.f, 0.f};
  f32x4 acc[4][2];
  #pragma unroll
  for (int i = 0; i < 4; ++i)
    #pragma unroll
    for (int j = 0; j < 2; ++j) acc[i][j] = zero;

  for (int k0 = 0; k0 < K; k0 += 32) {
    __syncthreads();
    #pragma unroll
    for (int t = 0; t < 2; ++t) {
      int s = t*256 + tid;
      int g = s >> 7, r = s & 127;
      *(uint4*)&As[s*8] = *(const uint4*)(A + (size_t)(row0 + r)*K + k0 + g*8);
    }
    {
      int g = tid >> 6, r = tid & 63;
      size_t offW = (size_t)(col0 + r)*K + k0 + g*8;
      if (is32) {
        const float* Wf = (const float*)W + offW;
        *(uint4*)&Ws[tid*8] = pack8_f32(((const float4*)Wf)[0], ((const float4*)Wf)[1]);
      } else {
        *(uint4*)&Ws[tid*8] = *(const uint4*)((const bf16*)W + offW);
      }
    }
    __syncthreads();
    bf16x8 af[4], wf[2];
    #pragma unroll
    for (int mt = 0; mt < 4; ++mt)
      af[mt] = *(const bf16x8*)&As[(quad*128 + wm*64 + mt*16 + l16)*8];
    #pragma unroll
    for (int nt = 0; nt < 2; ++nt)
      wf[nt] = *(const bf16x8*)&Ws[(quad*64 + wn*32 + nt*16 + l16)*8];
    #pragma unroll
    for (int mt = 0; mt < 4; ++mt)
      #pragma unroll
      for (int nt = 0; nt < 2; ++nt)
        acc[mt][nt] = __builtin_amdgcn_mfma_f32_16x16x32_bf16(af[mt], wf[nt], acc[mt][nt], 0, 0, 0);
  }
  #pragma unroll
  for (int nt = 0; nt < 2; ++nt) {
    int c = col0 + wn*32 + nt*16 + l16;
    float bv = is32 ? ((const float*)Bv)[c] : __bfloat162float(((const bf16*)Bv)[c]);
    #pragma unroll
    for (int mt = 0; mt < 4; ++mt) {
      int r = row0 + wm*64 + mt*16 + quad*4;
      #pragma unroll
      for (int j = 0; j < 4; ++j) {
        float outv = acc[mt][nt][j] + bv;
        size_t idx = (size_t)(r + j)*N + c;
        if (is32) ((float*)C)[idx] = outv;
        else      ((bf16*)C)[idx]  = __float2bfloat16(outv);
      }
    }
  }
}

// ---------------------------------------------------------------------------
// Flash attention v2: 512 threads (8 waves x 16 q-rows), q-tile 128, K-tile 128.
// S^T = K Q^T, O^T = V^T P^T. Q frags live in registers (8 VGPR) so the Q
// staging LDS region is reused for Ps -> 64 KB total, 2 blocks/CU, 16 waves/CU.
// Softmax in log2 domain (log2e folded into Q projection) -> raw v_exp_f32.
// 2 barriers per K-tile (Ps rows are wave-private).
// ---------------------------------------------------------------------------
__global__ __launch_bounds__(512, 4) void attn_fused(
    const bf16* __restrict__ Qp, const bf16* __restrict__ Kp,
    const bf16* __restrict__ Vp, bf16* __restrict__ Ao)
{
  __shared__ __align__(16) bf16 UN[128*128];    // 32 KB: Qs staging then Ps
  __shared__ __align__(16) bf16 Ks[8*128*8];    // 16 KB
  __shared__ __align__(16) bf16 Vt[64*16*8];    // 16 KB  V^T swizzled

  const int tid  = threadIdx.x;
  const int lane = tid & 63, wave = tid >> 6;
  const int quad = lane >> 4, l16 = lane & 15;
  const int qt = blockIdx.x, h = blockIdx.y, b = blockIdx.z;
  const int q0 = qt * 128;
  const bf16* Qb = Qp + ((size_t)b*SEQ + q0)*D_MODEL + h*DHEAD;
  const bf16* Kb = Kp + (size_t)b*SEQ*D_MODEL + h*DHEAD;
  const bf16* Vb = Vp + (size_t)b*SEQ*D_MODEL + h*DHEAD;

  // stage Q (1024 slots of 16B) via DMA into UN's first 16 KB
  #pragma unroll
  for (int t = 0; t < 2; ++t) {
    int s = t*512 + tid;
    int g = s >> 7, r = s & 127;
    lds_dma16(Qb + (size_t)r*D_MODEL + g*8, &UN[s*8]);
  }
  __syncthreads();

  const int wq0 = wave * 16;
  const int q   = wq0 + l16;          // this lane's q row (softmax/PV view)
  // Q B-operand frags: B[k = ks*32+quad*8+j][n=q] = Q[q][ks*32+quad*8+j]
  bf16x8 qa[2];
  #pragma unroll
  for (int ks = 0; ks < 2; ++ks)
    qa[ks] = *(const bf16x8*)&UN[((ks*4 + quad)*128 + q)*8];
  __syncthreads();                    // all Q reads done; UN becomes Ps
  bf16* Ps = UN;
  const int swz = (l16 & 7) << 1;     // Ps chunk swizzle (bit0 preserved)

  const f32x4 zero = {0.f, 0.f, 0.f, 0.f};
  f32x4 acc_o[4];
  #pragma unroll
  for (int dt = 0; dt < 4; ++dt) acc_o[dt] = zero;
  float m_s = -1e30f, l_s = 0.f;

  for (int kt = 0; kt < SEQ/128; ++kt) {
    const bf16* Kt_ = Kb + (size_t)kt*128*D_MODEL;
    const bf16* Vs_ = Vb + (size_t)kt*128*D_MODEL;
    #pragma unroll
    for (int t = 0; t < 2; ++t) {
      int s = t*512 + tid;
      int g = s >> 7, kk = s & 127;
      lds_dma16(Kt_ + (size_t)kk*D_MODEL + g*8, &Ks[s*8]);
    }
    #pragma unroll
    for (int t = 0; t < 2; ++t) {
      int c = t*512 + tid;
      int key = c >> 3, g8 = c & 7;
      uint4 raw = *(const uint4*)(Vs_ + (size_t)key*D_MODEL + g8*8);
      const bf16* e = (const bf16*)&raw;
      int gk = key >> 3, kb_i = key & 7;
      #pragma unroll
      for (int i = 0; i < 8; ++i) {
        int n = g8*8 + i;
        int sw = (gk + n + (n >> 3)) & 15;
        Vt[(n*16 + sw)*8 + kb_i] = e[i];
      }
    }
    __syncthreads();

    // ---- S^T = K Q^T : D[key = kt2*16+quad*4+j][q = l16-col] ----
    f32x4 sc[8];
    #pragma unroll
    for (int kt2 = 0; kt2 < 8; ++kt2) sc[kt2] = zero;
    #pragma unroll
    for (int ks = 0; ks < 2; ++ks) {
      bf16x8 kf[8];
      #pragma unroll
      for (int kt2 = 0; kt2 < 8; ++kt2)
        kf[kt2] = *(const bf16x8*)&Ks[((ks*4 + quad)*128 + kt2*16 + l16)*8];
      #pragma unroll
      for (int kt2 = 0; kt2 < 8; ++kt2)
        sc[kt2] = __builtin_amdgcn_mfma_f32_16x16x32_bf16(kf[kt2], qa[ks], sc[kt2], 0, 0, 0);
    }

    // ---- online softmax in log2 domain; lane owns q (x4 quads) ----
    float vmax = -1e30f;
    #pragma unroll
    for (int kt2 = 0; kt2 < 8; ++kt2) {
      f32x4 s4 = sc[kt2];
      vmax = fmaxf(vmax, fmaxf(fmaxf(s4[0], s4[1]), fmaxf(s4[2], s4[3])));
    }
    vmax = fmaxf(vmax, __shfl_xor(vmax, 16));
    vmax = fmaxf(vmax, __shfl_xor(vmax, 32));
    float mnew  = fmaxf(m_s, vmax);
    float alpha = __builtin_amdgcn_exp2f(m_s - mnew);
    float rs = 0.f;
    #pragma unroll
    for (int kt2 = 0; kt2 < 8; ++kt2) {
      float p0 = __builtin_amdgcn_exp2f(sc[kt2][0] - mnew);
      float p1 = __builtin_amdgcn_exp2f(sc[kt2][1] - mnew);
      float p2 = __builtin_amdgcn_exp2f(sc[kt2][2] - mnew);
      float p3 = __builtin_amdgcn_exp2f(sc[kt2][3] - mnew);
      rs += (p0 + p1) + (p2 + p3);
      union { uint2 u; bf16 hh[4]; } pk;
      pk.hh[0] = __float2bfloat16(p0); pk.hh[1] = __float2bfloat16(p1);
      pk.hh[2] = __float2bfloat16(p2); pk.hh[3] = __float2bfloat16(p3);
      int phys = (kt2*4 + quad) ^ swz;
      *(uint2*)&Ps[q*128 + phys*4] = pk.u;
    }
    rs += __shfl_xor(rs, 16);
    rs += __shfl_xor(rs, 32);
    l_s = l_s*alpha + rs;
    m_s = mnew;
    #pragma unroll
    for (int dt = 0; dt < 4; ++dt) acc_o[dt] = acc_o[dt] * alpha;
    // no barrier: Ps rows are wave-private, lgkmcnt orders ds_write->ds_read

    // ---- O^T += V^T P^T ----
    #pragma unroll
    for (int ks2 = 0; ks2 < 4; ++ks2) {
      bf16x8 vf[4], pa;
      #pragma unroll
      for (int dt = 0; dt < 4; ++dt) {
        int n = dt*16 + l16;
        int sw = (ks2*4 + quad + n + (n >> 3)) & 15;
        vf[dt] = *(const bf16x8*)&Vt[(n*16 + sw)*8];
      }
      int phys = (ks2*8 + quad*2) ^ swz;
      pa = *(const bf16x8*)&Ps[q*128 + phys*4];
      #pragma unroll
      for (int dt = 0; dt < 4; ++dt)
        acc_o[dt] = __builtin_amdgcn_mfma_f32_16x16x32_bf16(vf[dt], pa, acc_o[dt], 0, 0, 0);
    }
    __syncthreads();   // done with Ks/Vt before restaging
  }

  // ---- epilogue: lane holds O[q][d = dt*16+quad*4+j] ----
  bf16* Ob = Ao + ((size_t)b*SEQ + q0)*D_MODEL + h*DHEAD;
  float inv = 1.f / l_s;
  #pragma unroll
  for (int dt = 0; dt < 4; ++dt) {
    union { uint2 u; bf16 hh[4]; } pk;
    #pragma unroll
    for (int j = 0; j < 4; ++j) pk.hh[j] = __float2bfloat16(acc_o[dt][j] * inv);
    *(uint2*)(Ob + (size_t)q*D_MODEL + dt*16 + quad*4) = pk.u;
  }
}

// ---------------------------------------------------------------------------
extern "C" void kernel_launch(void* const* d_in, const int* in_sizes, int n_in,
                              void* d_out, int out_size, void* d_ws, size_t ws_size,
                              hipStream_t stream) {
  const void* q   = d_in[0];
  const void* k   = d_in[1];
  const void* v   = d_in[2];
  const void* w_q = d_in[3];
  const void* b_q = d_in[4];
  const void* w_k = d_in[5];
  const void* b_k = d_in[6];
  const void* w_v = d_in[7];
  const void* b_v = d_in[8];
  const void* w_o = d_in[9];
  const void* b_o = d_in[10];

  const size_t nbuf  = (size_t)MROWS * D_MODEL;      // 4.19M elems, 8.39 MB bf16
  const size_t wbuf  = (size_t)D_MODEL * D_MODEL;    // 1.05M elems, 2.10 MB bf16
  int* flag = (int*)d_ws;

  dim3 blk(256);
  probe_dtype<<<1, 256, 0, stream>>>(w_q, flag);

  const size_t needA = 256 + 3*nbuf*2 + 4*wbuf*2 + nbuf*2;  // 41.9 MB
  if (ws_size >= needA) {
    // ---------------- PATH A: pre-convert + DMA GEMMs ----------------
    bf16* qc  = (bf16*)((char*)d_ws + 256);
    bf16* kc  = qc  + nbuf;
    bf16* vc  = kc  + nbuf;
    bf16* wqc = vc  + nbuf;
    bf16* wkc = wqc + wbuf;
    bf16* wvc = wkc + wbuf;
    bf16* woc = wvc + wbuf;
    bf16* Qp  = woc + wbuf;
    bf16* Kp  = (bf16*)d_out;           // d_out scratch (fp32 out = 16.8 MB)
    bf16* Vp  = Kp + nbuf;
    bf16* Ao  = Qp;                     // alias: block-local slices only

    dim3 gc(512, 7);
    convert7<<<gc, blk, 0, stream>>>(q, k, v, w_q, w_k, w_v, w_o,
                                     qc, kc, vc, wqc, wkc, wvc, woc, flag);
    dim3 g3(D_MODEL/128, MROWS/128, 3);
    gemm3_dma<<<g3, blk, 0, stream>>>(qc, kc, vc, wqc, wkc, wvc,
                                      b_q, b_k, b_v, Qp, Kp, Vp, flag);
    dim3 ga(SEQ/128, NHEAD, BATCH);
    attn_fused<<<ga, dim3(512), 0, stream>>>(Qp, Kp, Vp, Ao);
    dim3 go(D_MODEL/64, MROWS/128);
    gemm_out_dma<<<go, blk, 0, stream>>>(Ao, woc, b_o, d_out, flag);
  } else {
    // ---------------- PATH B: round-3 fused-convert fallback ----------------
    bf16* Qp = (bf16*)((char*)d_ws + 256);
    bf16* Vp = Qp + nbuf;
    bf16* Kp = (bf16*)d_out;
    bf16* Ao = Qp;
    dim3 g3(D_MODEL/128, MROWS/128, 3);
    gemm3_fused<<<g3, blk, 0, stream>>>(q, k, v, w_q, w_k, w_v,
                                        b_q, b_k, b_v, Qp, Kp, Vp, flag);
    dim3 ga(SEQ/128, NHEAD, BATCH);
    attn_fused<<<ga, dim3(512), 0, stream>>>(Qp, Kp, Vp, Ao);
    dim3 go(D_MODEL/64, MROWS/128);
    gemm_out_fused<<<go, blk, 0, stream>>>(Ao, w_o, b_o, d_out, flag);
  }
}

// Round 5
// 309.663 us; speedup vs baseline: 1.7302x; 1.0144x over previous
//
#include <hip/hip_runtime.h>
#include <hip/hip_bf16.h>

typedef __hip_bfloat16 bf16;
typedef short bf16x8 __attribute__((ext_vector_type(8)));   // 8 bf16 = 4 VGPRs
typedef float f32x4 __attribute__((ext_vector_type(4)));    // C/D frag

#define D_MODEL 1024
#define SEQ     2048
#define NHEAD   16
#define DHEAD   64
#define BATCH   2
#define MROWS   (BATCH*SEQ)   // 4096
#define LOG2E   1.4426950408889634f

// async global->LDS, 16B per lane (m97 lever). Dest must be wave-uniform
// base + lane*16 (m104/m108) — all call sites below satisfy this.
__device__ __forceinline__ void lds_dma16(const bf16* g, bf16* l) {
  __builtin_amdgcn_global_load_lds(
      (const __attribute__((address_space(1))) void*)g,
      (__attribute__((address_space(3))) void*)l, 16, 0, 0);
}

__device__ __forceinline__ uint4 pack8_f32(const float4 x0, const float4 x1) {
  union { uint4 q; bf16 h[8]; } pk;
  pk.h[0]=__float2bfloat16(x0.x); pk.h[1]=__float2bfloat16(x0.y);
  pk.h[2]=__float2bfloat16(x0.z); pk.h[3]=__float2bfloat16(x0.w);
  pk.h[4]=__float2bfloat16(x1.x); pk.h[5]=__float2bfloat16(x1.y);
  pk.h[6]=__float2bfloat16(x1.z); pk.h[7]=__float2bfloat16(x1.w);
  return pk.q;
}

// ---------------------------------------------------------------------------
// Convert 7 fp32 buffers -> bf16. grid (512,7): z<3 = q,k,v; z>=3 = weights.
// ---------------------------------------------------------------------------
__global__ __launch_bounds__(256) void convert7(
    const float* s0, const float* s1, const float* s2, const float* s3,
    const float* s4, const float* s5, const float* s6,
    bf16* d0, bf16* d1, bf16* d2, bf16* d3, bf16* d4, bf16* d5, bf16* d6)
{
  const float* S[7] = {s0,s1,s2,s3,s4,s5,s6};
  bf16*        D[7] = {d0,d1,d2,d3,d4,d5,d6};
  const int z = blockIdx.y;
  const int n8 = (z < 3) ? (MROWS*D_MODEL/8) : (D_MODEL*D_MODEL/8);
  for (int i = blockIdx.x*256 + threadIdx.x; i < n8; i += 512*256) {
    float4 a = ((const float4*)S[z])[2*i];
    float4 b = ((const float4*)S[z])[2*i+1];
    ((uint4*)D[z])[i] = pack8_f32(a, b);
  }
}

// ---------------------------------------------------------------------------
// PATH A: fused QKV GEMM, bf16 inputs via global_load_lds, BK=64.
// z=0: Q (scale 1/8*log2e), z=1: K, z=2: V written TRANSPOSED
// (VpT[(b*1024 + h*64 + d)*SEQ + s], token-contiguous 8B stores).
// 128x128 tile; grid (8,32,3) = 768 blocks = 3/CU.
// ---------------------------------------------------------------------------
__global__ __launch_bounds__(256) void gemm3_dma(
    const bf16* A0, const bf16* A1, const bf16* A2,
    const bf16* W0, const bf16* W1, const bf16* W2,
    const float* B0, const float* B1, const float* B2,
    bf16* C0, bf16* C1, bf16* VpT)
{
  __shared__ __align__(16) bf16 As[8*128*8];   // 16 KB
  __shared__ __align__(16) bf16 Ws[8*128*8];   // 16 KB
  const int z = blockIdx.z;
  const bf16* A = (z == 0) ? A0 : (z == 1) ? A1 : A2;
  const bf16* W = (z == 0) ? W0 : (z == 1) ? W1 : W2;
  const float* Bv = (z == 0) ? B0 : (z == 1) ? B1 : B2;
  const int K = D_MODEL, N = D_MODEL;
  const int tid  = threadIdx.x;
  const int lane = tid & 63, wave = tid >> 6;
  const int wm   = wave >> 1, wn = wave & 1;
  const int quad = lane >> 4, l16 = lane & 15;
  const int row0 = blockIdx.y * 128, col0 = blockIdx.x * 128;

  const f32x4 zero = {0.f, 0.f, 0.f, 0.f};
  f32x4 acc[4][4];
  #pragma unroll
  for (int i = 0; i < 4; ++i)
    #pragma unroll
    for (int j = 0; j < 4; ++j) acc[i][j] = zero;

  for (int k0 = 0; k0 < K; k0 += 64) {
    __syncthreads();
    #pragma unroll
    for (int t = 0; t < 4; ++t) {
      int s = t*256 + tid;
      int g = s >> 7, r = s & 127;
      lds_dma16(A + (size_t)(row0 + r)*K + k0 + g*8, &As[s*8]);
      lds_dma16(W + (size_t)(col0 + r)*K + k0 + g*8, &Ws[s*8]);
    }
    __syncthreads();
    #pragma unroll
    for (int ks = 0; ks < 2; ++ks) {
      bf16x8 af[4], wf[4];
      #pragma unroll
      for (int mt = 0; mt < 4; ++mt)
        af[mt] = *(const bf16x8*)&As[((ks*4 + quad)*128 + wm*64 + mt*16 + l16)*8];
      #pragma unroll
      for (int nt = 0; nt < 4; ++nt)
        wf[nt] = *(const bf16x8*)&Ws[((ks*4 + quad)*128 + wn*64 + nt*16 + l16)*8];
      #pragma unroll
      for (int mt = 0; mt < 4; ++mt)
        #pragma unroll
        for (int nt = 0; nt < 4; ++nt)
          acc[mt][nt] = __builtin_amdgcn_mfma_f32_16x16x32_bf16(af[mt], wf[nt], acc[mt][nt], 0, 0, 0);
    }
  }

  if (z < 2) {
    bf16* C = (z == 0) ? C0 : C1;
    const float scale = (z == 0) ? 0.125f*LOG2E : 1.0f;
    #pragma unroll
    for (int nt = 0; nt < 4; ++nt) {
      int c = col0 + wn*64 + nt*16 + l16;
      float bv = Bv[c];
      #pragma unroll
      for (int mt = 0; mt < 4; ++mt) {
        int r = row0 + wm*64 + mt*16 + quad*4;
        #pragma unroll
        for (int j = 0; j < 4; ++j)
          C[(size_t)(r + j)*N + c] = __float2bfloat16((acc[mt][nt][j] + bv) * scale);
      }
    }
  } else {
    // V transposed: VpT[(bb*1024 + c)*SEQ + s], j spans tokens (contiguous)
    const int bb = row0 >> 11;
    const int sbase = (row0 & 2047) + wm*64;
    #pragma unroll
    for (int nt = 0; nt < 4; ++nt) {
      int c = col0 + wn*64 + nt*16 + l16;
      float bv = Bv[c];
      bf16* col = VpT + (size_t)((bb << 10) + c) * SEQ;
      #pragma unroll
      for (int mt = 0; mt < 4; ++mt) {
        int s = sbase + mt*16 + quad*4;
        union { uint2 u; bf16 h[4]; } pk;
        #pragma unroll
        for (int j = 0; j < 4; ++j) pk.h[j] = __float2bfloat16(acc[mt][nt][j] + bv);
        *(uint2*)(col + s) = pk.u;
      }
    }
  }
}

// ---------------------------------------------------------------------------
// PATH A: output projection, BK=64, 128x64 tile; grid (16,32) = 512 blocks.
// Writes fp32 d_out.
// ---------------------------------------------------------------------------
__global__ __launch_bounds__(256) void gemm_out_dma(
    const bf16* __restrict__ A, const bf16* __restrict__ W,
    const float* __restrict__ Bv, float* __restrict__ C)
{
  __shared__ __align__(16) bf16 As[8*128*8];   // 16 KB
  __shared__ __align__(16) bf16 Ws[8*64*8];    // 8 KB
  const int K = D_MODEL, N = D_MODEL;
  const int tid  = threadIdx.x;
  const int lane = tid & 63, wave = tid >> 6;
  const int wm   = wave >> 1, wn = wave & 1;
  const int quad = lane >> 4, l16 = lane & 15;
  const int row0 = blockIdx.y * 128, col0 = blockIdx.x * 64;

  const f32x4 zero = {0.f, 0.f, 0.f, 0.f};
  f32x4 acc[4][2];
  #pragma unroll
  for (int i = 0; i < 4; ++i)
    #pragma unroll
    for (int j = 0; j < 2; ++j) acc[i][j] = zero;

  for (int k0 = 0; k0 < K; k0 += 64) {
    __syncthreads();
    #pragma unroll
    for (int t = 0; t < 4; ++t) {
      int s = t*256 + tid;
      int g = s >> 7, r = s & 127;
      lds_dma16(A + (size_t)(row0 + r)*K + k0 + g*8, &As[s*8]);
    }
    #pragma unroll
    for (int t = 0; t < 2; ++t) {
      int s = t*256 + tid;
      int g = s >> 6, r = s & 63;
      lds_dma16(W + (size_t)(col0 + r)*K + k0 + g*8, &Ws[s*8]);
    }
    __syncthreads();
    #pragma unroll
    for (int ks = 0; ks < 2; ++ks) {
      bf16x8 af[4], wf[2];
      #pragma unroll
      for (int mt = 0; mt < 4; ++mt)
        af[mt] = *(const bf16x8*)&As[((ks*4 + quad)*128 + wm*64 + mt*16 + l16)*8];
      #pragma unroll
      for (int nt = 0; nt < 2; ++nt)
        wf[nt] = *(const bf16x8*)&Ws[((ks*4 + quad)*64 + wn*32 + nt*16 + l16)*8];
      #pragma unroll
      for (int mt = 0; mt < 4; ++mt)
        #pragma unroll
        for (int nt = 0; nt < 2; ++nt)
          acc[mt][nt] = __builtin_amdgcn_mfma_f32_16x16x32_bf16(af[mt], wf[nt], acc[mt][nt], 0, 0, 0);
    }
  }

  #pragma unroll
  for (int nt = 0; nt < 2; ++nt) {
    int c = col0 + wn*32 + nt*16 + l16;
    float bv = Bv[c];
    #pragma unroll
    for (int mt = 0; mt < 4; ++mt) {
      int r = row0 + wm*64 + mt*16 + quad*4;
      #pragma unroll
      for (int j = 0; j < 4; ++j)
        C[(size_t)(r + j)*N + c] = acc[mt][nt][j] + bv;
    }
  }
}

// ---------------------------------------------------------------------------
// PATH B fallback (small ws): fused fp32->bf16 staging GEMMs, BK=32.
// ---------------------------------------------------------------------------
__global__ __launch_bounds__(256) void gemm3_fused(
    const float* A0, const float* A1, const float* A2,
    const float* W0, const float* W1, const float* W2,
    const float* B0, const float* B1, const float* B2,
    bf16* C0, bf16* C1, bf16* VpT)
{
  __shared__ __align__(16) bf16 As[4*128*8];
  __shared__ __align__(16) bf16 Ws[4*128*8];
  const int z = blockIdx.z;
  const float* A = (z == 0) ? A0 : (z == 1) ? A1 : A2;
  const float* W = (z == 0) ? W0 : (z == 1) ? W1 : W2;
  const float* Bv = (z == 0) ? B0 : (z == 1) ? B1 : B2;
  const int K = D_MODEL, N = D_MODEL;
  const int tid  = threadIdx.x;
  const int lane = tid & 63, wave = tid >> 6;
  const int wm   = wave >> 1, wn = wave & 1;
  const int quad = lane >> 4, l16 = lane & 15;
  const int row0 = blockIdx.y * 128, col0 = blockIdx.x * 128;

  const f32x4 zero = {0.f, 0.f, 0.f, 0.f};
  f32x4 acc[4][4];
  #pragma unroll
  for (int i = 0; i < 4; ++i)
    #pragma unroll
    for (int j = 0; j < 4; ++j) acc[i][j] = zero;

  for (int k0 = 0; k0 < K; k0 += 32) {
    __syncthreads();
    #pragma unroll
    for (int t = 0; t < 2; ++t) {
      int s = t*256 + tid;
      int g = s >> 7, r = s & 127;
      const float* Af = A + (size_t)(row0 + r)*K + k0 + g*8;
      *(uint4*)&As[s*8] = pack8_f32(((const float4*)Af)[0], ((const float4*)Af)[1]);
      const float* Wf = W + (size_t)(col0 + r)*K + k0 + g*8;
      *(uint4*)&Ws[s*8] = pack8_f32(((const float4*)Wf)[0], ((const float4*)Wf)[1]);
    }
    __syncthreads();
    bf16x8 af[4], wf[4];
    #pragma unroll
    for (int mt = 0; mt < 4; ++mt)
      af[mt] = *(const bf16x8*)&As[(quad*128 + wm*64 + mt*16 + l16)*8];
    #pragma unroll
    for (int nt = 0; nt < 4; ++nt)
      wf[nt] = *(const bf16x8*)&Ws[(quad*128 + wn*64 + nt*16 + l16)*8];
    #pragma unroll
    for (int mt = 0; mt < 4; ++mt)
      #pragma unroll
      for (int nt = 0; nt < 4; ++nt)
        acc[mt][nt] = __builtin_amdgcn_mfma_f32_16x16x32_bf16(af[mt], wf[nt], acc[mt][nt], 0, 0, 0);
  }

  if (z < 2) {
    bf16* C = (z == 0) ? C0 : C1;
    const float scale = (z == 0) ? 0.125f*LOG2E : 1.0f;
    #pragma unroll
    for (int nt = 0; nt < 4; ++nt) {
      int c = col0 + wn*64 + nt*16 + l16;
      float bv = Bv[c];
      #pragma unroll
      for (int mt = 0; mt < 4; ++mt) {
        int r = row0 + wm*64 + mt*16 + quad*4;
        #pragma unroll
        for (int j = 0; j < 4; ++j)
          C[(size_t)(r + j)*N + c] = __float2bfloat16((acc[mt][nt][j] + bv) * scale);
      }
    }
  } else {
    const int bb = row0 >> 11;
    const int sbase = (row0 & 2047) + wm*64;
    #pragma unroll
    for (int nt = 0; nt < 4; ++nt) {
      int c = col0 + wn*64 + nt*16 + l16;
      float bv = Bv[c];
      bf16* col = VpT + (size_t)((bb << 10) + c) * SEQ;
      #pragma unroll
      for (int mt = 0; mt < 4; ++mt) {
        int s = sbase + mt*16 + quad*4;
        union { uint2 u; bf16 h[4]; } pk;
        #pragma unroll
        for (int j = 0; j < 4; ++j) pk.h[j] = __float2bfloat16(acc[mt][nt][j] + bv);
        *(uint2*)(col + s) = pk.u;
      }
    }
  }
}

__global__ __launch_bounds__(256) void gemm_out_fused(
    const bf16* __restrict__ A, const float* __restrict__ W,
    const float* __restrict__ Bv, float* __restrict__ C)
{
  __shared__ __align__(16) bf16 As[4*128*8];
  __shared__ __align__(16) bf16 Ws[4*64*8];
  const int K = D_MODEL, N = D_MODEL;
  const int tid  = threadIdx.x;
  const int lane = tid & 63, wave = tid >> 6;
  const int wm   = wave >> 1, wn = wave & 1;
  const int quad = lane >> 4, l16 = lane & 15;
  const int row0 = blockIdx.y * 128, col0 = blockIdx.x * 64;

  const f32x4 zero = {0.f, 0.f, 0.f, 0.f};
  f32x4 acc[4][2];
  #pragma unroll
  for (int i = 0; i < 4; ++i)
    #pragma unroll
    for (int j = 0; j < 2; ++j) acc[i][j] = zero;

  for (int k0 = 0; k0 < K; k0 += 32) {
    __syncthreads();
    #pragma unroll
    for (int t = 0; t < 2; ++t) {
      int s = t*256 + tid;
      int g = s >> 7, r = s & 127;
      *(uint4*)&As[s*8] = *(const uint4*)(A + (size_t)(row0 + r)*K + k0 + g*8);
    }
    {
      int g = tid >> 6, r = tid & 63;
      const float* Wf = W + (size_t)(col0 + r)*K + k0 + g*8;
      *(uint4*)&Ws[tid*8] = pack8_f32(((const float4*)Wf)[0], ((const float4*)Wf)[1]);
    }
    __syncthreads();
    bf16x8 af[4], wf[2];
    #pragma unroll
    for (int mt = 0; mt < 4; ++mt)
      af[mt] = *(const bf16x8*)&As[(quad*128 + wm*64 + mt*16 + l16)*8];
    #pragma unroll
    for (int nt = 0; nt < 2; ++nt)
      wf[nt] = *(const bf16x8*)&Ws[(quad*64 + wn*32 + nt*16 + l16)*8];
    #pragma unroll
    for (int mt = 0; mt < 4; ++mt)
      #pragma unroll
      for (int nt = 0; nt < 2; ++nt)
        acc[mt][nt] = __builtin_amdgcn_mfma_f32_16x16x32_bf16(af[mt], wf[nt], acc[mt][nt], 0, 0, 0);
  }
  #pragma unroll
  for (int nt = 0; nt < 2; ++nt) {
    int c = col0 + wn*32 + nt*16 + l16;
    float bv = Bv[c];
    #pragma unroll
    for (int mt = 0; mt < 4; ++mt) {
      int r = row0 + wm*64 + mt*16 + quad*4;
      #pragma unroll
      for (int j = 0; j < 4; ++j)
        C[(size_t)(r + j)*N + c] = acc[mt][nt][j] + bv;
    }
  }
}

// ---------------------------------------------------------------------------
// Flash attention: 512 threads (8 waves x 16 q-rows), q-tile 128, K-tile 128.
// S^T = K Q^T, O^T = V^T P^T, log2-domain softmax (log2e folded into Q proj).
// V comes pre-transposed from global (VpT) -> staging is coalesced 16B loads
// + single b128 swizzled LDS write (was 16 scalar u16 writes). 64 KB LDS.
// ---------------------------------------------------------------------------
__global__ __launch_bounds__(512) void attn_fused(
    const bf16* __restrict__ Qp, const bf16* __restrict__ Kp,
    const bf16* __restrict__ VpT, bf16* __restrict__ Ao)
{
  __shared__ __align__(16) bf16 UN[128*128];    // 32 KB: Qs staging then Ps
  __shared__ __align__(16) bf16 Ks[8*128*8];    // 16 KB
  __shared__ __align__(16) bf16 Vt[64*16*8];    // 16 KB  V^T swizzled

  const int tid  = threadIdx.x;
  const int lane = tid & 63, wave = tid >> 6;
  const int quad = lane >> 4, l16 = lane & 15;
  const int qt = blockIdx.x, h = blockIdx.y, b = blockIdx.z;
  const int q0 = qt * 128;
  const bf16* Qb = Qp + ((size_t)b*SEQ + q0)*D_MODEL + h*DHEAD;
  const bf16* Kb = Kp + (size_t)b*SEQ*D_MODEL + h*DHEAD;
  const bf16* Vg = VpT + (size_t)((b << 10) + h*DHEAD) * SEQ;  // rows: d

  // stage Q once via DMA into UN's first 16 KB
  #pragma unroll
  for (int t = 0; t < 2; ++t) {
    int s = t*512 + tid;
    int g = s >> 7, r = s & 127;
    lds_dma16(Qb + (size_t)r*D_MODEL + g*8, &UN[s*8]);
  }
  __syncthreads();

  const int wq0 = wave * 16;
  const int q   = wq0 + l16;
  bf16x8 qa[2];                       // Q B-operand frags in registers
  #pragma unroll
  for (int ks = 0; ks < 2; ++ks)
    qa[ks] = *(const bf16x8*)&UN[((ks*4 + quad)*128 + q)*8];
  __syncthreads();                    // Q reads done; UN becomes Ps
  bf16* Ps = UN;
  const int swz = (l16 & 7) << 1;

  const f32x4 zero = {0.f, 0.f, 0.f, 0.f};
  f32x4 acc_o[4];
  #pragma unroll
  for (int dt = 0; dt < 4; ++dt) acc_o[dt] = zero;
  float m_s = -1e30f, l_s = 0.f;

  for (int kt = 0; kt < SEQ/128; ++kt) {
    // K tile via DMA
    #pragma unroll
    for (int t = 0; t < 2; ++t) {
      int s = t*512 + tid;
      int g = s >> 7, kk = s & 127;
      lds_dma16(Kb + (size_t)(kt*128 + kk)*D_MODEL + g*8, &Ks[s*8]);
    }
    // V^T tile: coalesced 16B loads, b128 swizzled writes
    #pragma unroll
    for (int t = 0; t < 2; ++t) {
      int c = t*512 + tid;            // 1024 chunks: (d=n, keygroup gk)
      int n = c >> 4, gk = c & 15;
      uint4 raw = *(const uint4*)(Vg + (size_t)n*SEQ + kt*128 + gk*8);
      int sw = (gk + n + (n >> 3)) & 15;
      *(uint4*)&Vt[(n*16 + sw)*8] = raw;
    }
    __syncthreads();

    // ---- S^T = K Q^T : D[key = kt2*16+quad*4+j][q = l16] ----
    f32x4 sc[8];
    #pragma unroll
    for (int kt2 = 0; kt2 < 8; ++kt2) sc[kt2] = zero;
    #pragma unroll
    for (int ks = 0; ks < 2; ++ks) {
      bf16x8 kf[8];
      #pragma unroll
      for (int kt2 = 0; kt2 < 8; ++kt2)
        kf[kt2] = *(const bf16x8*)&Ks[((ks*4 + quad)*128 + kt2*16 + l16)*8];
      #pragma unroll
      for (int kt2 = 0; kt2 < 8; ++kt2)
        sc[kt2] = __builtin_amdgcn_mfma_f32_16x16x32_bf16(kf[kt2], qa[ks], sc[kt2], 0, 0, 0);
    }

    // ---- online softmax (log2 domain); lane owns q across 4 quads ----
    float vmax = -1e30f;
    #pragma unroll
    for (int kt2 = 0; kt2 < 8; ++kt2) {
      f32x4 s4 = sc[kt2];
      vmax = fmaxf(vmax, fmaxf(fmaxf(s4[0], s4[1]), fmaxf(s4[2], s4[3])));
    }
    vmax = fmaxf(vmax, __shfl_xor(vmax, 16));
    vmax = fmaxf(vmax, __shfl_xor(vmax, 32));
    float mnew  = fmaxf(m_s, vmax);
    float alpha = __builtin_amdgcn_exp2f(m_s - mnew);
    float rs = 0.f;
    #pragma unroll
    for (int kt2 = 0; kt2 < 8; ++kt2) {
      float p0 = __builtin_amdgcn_exp2f(sc[kt2][0] - mnew);
      float p1 = __builtin_amdgcn_exp2f(sc[kt2][1] - mnew);
      float p2 = __builtin_amdgcn_exp2f(sc[kt2][2] - mnew);
      float p3 = __builtin_amdgcn_exp2f(sc[kt2][3] - mnew);
      rs += (p0 + p1) + (p2 + p3);
      union { uint2 u; bf16 hh[4]; } pk;
      pk.hh[0] = __float2bfloat16(p0); pk.hh[1] = __float2bfloat16(p1);
      pk.hh[2] = __float2bfloat16(p2); pk.hh[3] = __float2bfloat16(p3);
      int phys = (kt2*4 + quad) ^ swz;
      *(uint2*)&Ps[q*128 + phys*4] = pk.u;
    }
    rs += __shfl_xor(rs, 16);
    rs += __shfl_xor(rs, 32);
    l_s = l_s*alpha + rs;
    m_s = mnew;
    #pragma unroll
    for (int dt = 0; dt < 4; ++dt) acc_o[dt] = acc_o[dt] * alpha;
    // no barrier: Ps rows are wave-private; lgkmcnt orders write->read

    // ---- O^T += V^T P^T ----
    #pragma unroll
    for (int ks2 = 0; ks2 < 4; ++ks2) {
      bf16x8 vf[4], pa;
      #pragma unroll
      for (int dt = 0; dt < 4; ++dt) {
        int n = dt*16 + l16;
        int sw = (ks2*4 + quad + n + (n >> 3)) & 15;
        vf[dt] = *(const bf16x8*)&Vt[(n*16 + sw)*8];
      }
      int phys = (ks2*8 + quad*2) ^ swz;
      pa = *(const bf16x8*)&Ps[q*128 + phys*4];
      #pragma unroll
      for (int dt = 0; dt < 4; ++dt)
        acc_o[dt] = __builtin_amdgcn_mfma_f32_16x16x32_bf16(vf[dt], pa, acc_o[dt], 0, 0, 0);
    }
    __syncthreads();   // done with Ks/Vt before restaging
  }

  bf16* Ob = Ao + ((size_t)b*SEQ + q0)*D_MODEL + h*DHEAD;
  float inv = 1.f / l_s;
  #pragma unroll
  for (int dt = 0; dt < 4; ++dt) {
    union { uint2 u; bf16 hh[4]; } pk;
    #pragma unroll
    for (int j = 0; j < 4; ++j) pk.hh[j] = __float2bfloat16(acc_o[dt][j] * inv);
    *(uint2*)(Ob + (size_t)q*D_MODEL + dt*16 + quad*4) = pk.u;
  }
}

// ---------------------------------------------------------------------------
extern "C" void kernel_launch(void* const* d_in, const int* in_sizes, int n_in,
                              void* d_out, int out_size, void* d_ws, size_t ws_size,
                              hipStream_t stream) {
  const float* q   = (const float*)d_in[0];
  const float* k   = (const float*)d_in[1];
  const float* v   = (const float*)d_in[2];
  const float* w_q = (const float*)d_in[3];
  const float* b_q = (const float*)d_in[4];
  const float* w_k = (const float*)d_in[5];
  const float* b_k = (const float*)d_in[6];
  const float* w_v = (const float*)d_in[7];
  const float* b_v = (const float*)d_in[8];
  const float* w_o = (const float*)d_in[9];
  const float* b_o = (const float*)d_in[10];

  const size_t nbuf = (size_t)MROWS * D_MODEL;    // 4.19M elems
  const size_t wbuf = (size_t)D_MODEL * D_MODEL;  // 1.05M elems
  // d_out (fp32, 16.78 MB) doubles as scratch for Kp + VpT (exactly fits)
  bf16* Kp  = (bf16*)d_out;
  bf16* VpT = Kp + nbuf;

  const size_t needA = 256 + (3*nbuf + 4*wbuf + nbuf) * 2;  // ~41.9 MB
  if (ws_size >= needA) {
    bf16* qc  = (bf16*)((char*)d_ws + 256);
    bf16* kc  = qc  + nbuf;
    bf16* vc  = kc  + nbuf;
    bf16* wqc = vc  + nbuf;
    bf16* wkc = wqc + wbuf;
    bf16* wvc = wkc + wbuf;
    bf16* woc = wvc + wbuf;
    bf16* Qp  = woc + wbuf;
    bf16* Ao  = Qp;                   // alias: block-local slices only

    convert7<<<dim3(512,7), 256, 0, stream>>>(q, k, v, w_q, w_k, w_v, w_o,
                                              qc, kc, vc, wqc, wkc, wvc, woc);
    gemm3_dma<<<dim3(8,32,3), 256, 0, stream>>>(qc, kc, vc, wqc, wkc, wvc,
                                                b_q, b_k, b_v, Qp, Kp, VpT);
    attn_fused<<<dim3(16,16,2), 512, 0, stream>>>(Qp, Kp, VpT, Ao);
    gemm_out_dma<<<dim3(16,32), 256, 0, stream>>>(Ao, woc, b_o, (float*)d_out);
  } else {
    bf16* Qp = (bf16*)((char*)d_ws + 256);
    bf16* Ao = Qp;
    gemm3_fused<<<dim3(8,32,3), 256, 0, stream>>>(q, k, v, w_q, w_k, w_v,
                                                  b_q, b_k, b_v, Qp, Kp, VpT);
    attn_fused<<<dim3(16,16,2), 512, 0, stream>>>(Qp, Kp, VpT, Ao);
    gemm_out_fused<<<dim3(16,32), 256, 0, stream>>>(Ao, w_o, b_o, (float*)d_out);
  }
}

// Round 6
// 307.031 us; speedup vs baseline: 1.7451x; 1.0086x over previous
//
#include <hip/hip_runtime.h>
#include <hip/hip_bf16.h>

typedef __hip_bfloat16 bf16;
typedef short bf16x8 __attribute__((ext_vector_type(8)));   // 8 bf16 = 4 VGPRs
typedef float f32x4 __attribute__((ext_vector_type(4)));    // C/D frag

#define D_MODEL 1024
#define SEQ     2048
#define NHEAD   16
#define DHEAD   64
#define BATCH   2
#define MROWS   (BATCH*SEQ)   // 4096
#define LOG2E   1.4426950408889634f

// async global->LDS, 16B per lane (m97 lever). Dest = wave-uniform base +
// lane*16 (m104/m108) — all call sites satisfy this.
__device__ __forceinline__ void lds_dma16(const bf16* g, bf16* l) {
  __builtin_amdgcn_global_load_lds(
      (const __attribute__((address_space(1))) void*)g,
      (__attribute__((address_space(3))) void*)l, 16, 0, 0);
}

__device__ __forceinline__ uint4 pack8_f32(const float4 x0, const float4 x1) {
  union { uint4 q; bf16 h[8]; } pk;
  pk.h[0]=__float2bfloat16(x0.x); pk.h[1]=__float2bfloat16(x0.y);
  pk.h[2]=__float2bfloat16(x0.z); pk.h[3]=__float2bfloat16(x0.w);
  pk.h[4]=__float2bfloat16(x1.x); pk.h[5]=__float2bfloat16(x1.y);
  pk.h[6]=__float2bfloat16(x1.z); pk.h[7]=__float2bfloat16(x1.w);
  return pk.q;
}

// ---------------------------------------------------------------------------
// Convert 7 fp32 buffers -> bf16. grid (512,7).
// ---------------------------------------------------------------------------
__global__ __launch_bounds__(256) void convert7(
    const float* s0, const float* s1, const float* s2, const float* s3,
    const float* s4, const float* s5, const float* s6,
    bf16* d0, bf16* d1, bf16* d2, bf16* d3, bf16* d4, bf16* d5, bf16* d6)
{
  const float* S[7] = {s0,s1,s2,s3,s4,s5,s6};
  bf16*        D[7] = {d0,d1,d2,d3,d4,d5,d6};
  const int z = blockIdx.y;
  const int n8 = (z < 3) ? (MROWS*D_MODEL/8) : (D_MODEL*D_MODEL/8);
  for (int i = blockIdx.x*256 + threadIdx.x; i < n8; i += 512*256) {
    float4 a = ((const float4*)S[z])[2*i];
    float4 b = ((const float4*)S[z])[2*i+1];
    ((uint4*)D[z])[i] = pack8_f32(a, b);
  }
}

// ---------------------------------------------------------------------------
// PATH A: fused QKV GEMM, DMA staging, BK=64. z=0: Q (scale 1/8*log2e),
// z=1: K, z=2: V written TRANSPOSED into VpT[(b*1024+c)*SEQ + s].
// z<2 use SWAPPED mfma(wf, af) -> lane holds 4 consecutive OUTPUT COLUMNS
// -> vectorized 8B epilogue stores (the K=1024 epilogue-amortization fix).
// ---------------------------------------------------------------------------
__global__ __launch_bounds__(256) void gemm3_dma(
    const bf16* A0, const bf16* A1, const bf16* A2,
    const bf16* W0, const bf16* W1, const bf16* W2,
    const float* B0, const float* B1, const float* B2,
    bf16* C0, bf16* C1, bf16* VpT)
{
  __shared__ __align__(16) bf16 As[8*128*8];   // 16 KB
  __shared__ __align__(16) bf16 Ws[8*128*8];   // 16 KB
  const int z = blockIdx.z;
  const bf16* A = (z == 0) ? A0 : (z == 1) ? A1 : A2;
  const bf16* W = (z == 0) ? W0 : (z == 1) ? W1 : W2;
  const float* Bv = (z == 0) ? B0 : (z == 1) ? B1 : B2;
  const bool swapped = (z < 2);
  const int K = D_MODEL, N = D_MODEL;
  const int tid  = threadIdx.x;
  const int lane = tid & 63, wave = tid >> 6;
  const int wm   = wave >> 1, wn = wave & 1;
  const int quad = lane >> 4, l16 = lane & 15;
  const int row0 = blockIdx.y * 128, col0 = blockIdx.x * 128;

  const f32x4 zero = {0.f, 0.f, 0.f, 0.f};
  f32x4 acc[4][4];
  #pragma unroll
  for (int i = 0; i < 4; ++i)
    #pragma unroll
    for (int j = 0; j < 4; ++j) acc[i][j] = zero;

  for (int k0 = 0; k0 < K; k0 += 64) {
    __syncthreads();
    #pragma unroll
    for (int t = 0; t < 4; ++t) {
      int s = t*256 + tid;
      int g = s >> 7, r = s & 127;
      lds_dma16(A + (size_t)(row0 + r)*K + k0 + g*8, &As[s*8]);
      lds_dma16(W + (size_t)(col0 + r)*K + k0 + g*8, &Ws[s*8]);
    }
    __syncthreads();
    #pragma unroll
    for (int ks = 0; ks < 2; ++ks) {
      bf16x8 af[4], wf[4];
      #pragma unroll
      for (int mt = 0; mt < 4; ++mt)
        af[mt] = *(const bf16x8*)&As[((ks*4 + quad)*128 + wm*64 + mt*16 + l16)*8];
      #pragma unroll
      for (int nt = 0; nt < 4; ++nt)
        wf[nt] = *(const bf16x8*)&Ws[((ks*4 + quad)*128 + wn*64 + nt*16 + l16)*8];
      if (swapped) {
        #pragma unroll
        for (int mt = 0; mt < 4; ++mt)
          #pragma unroll
          for (int nt = 0; nt < 4; ++nt)
            acc[mt][nt] = __builtin_amdgcn_mfma_f32_16x16x32_bf16(wf[nt], af[mt], acc[mt][nt], 0, 0, 0);
      } else {
        #pragma unroll
        for (int mt = 0; mt < 4; ++mt)
          #pragma unroll
          for (int nt = 0; nt < 4; ++nt)
            acc[mt][nt] = __builtin_amdgcn_mfma_f32_16x16x32_bf16(af[mt], wf[nt], acc[mt][nt], 0, 0, 0);
      }
    }
  }

  if (swapped) {
    bf16* C = (z == 0) ? C0 : C1;
    const float scale = (z == 0) ? 0.125f*LOG2E : 1.0f;
    // D[c][m]: lane holds cols c0..c0+3 of row r -> 8B packed stores
    #pragma unroll
    for (int mt = 0; mt < 4; ++mt) {
      int r = row0 + wm*64 + mt*16 + l16;
      #pragma unroll
      for (int nt = 0; nt < 4; ++nt) {
        int c0 = col0 + wn*64 + nt*16 + quad*4;
        float4 b4 = *(const float4*)(Bv + c0);
        union { uint2 u; bf16 h[4]; } pk;
        pk.h[0] = __float2bfloat16((acc[mt][nt][0] + b4.x) * scale);
        pk.h[1] = __float2bfloat16((acc[mt][nt][1] + b4.y) * scale);
        pk.h[2] = __float2bfloat16((acc[mt][nt][2] + b4.z) * scale);
        pk.h[3] = __float2bfloat16((acc[mt][nt][3] + b4.w) * scale);
        *(uint2*)&C[(size_t)r*N + c0] = pk.u;
      }
    }
  } else {
    // V: D[m][c]; tokens quad*4+j contiguous -> 8B stores into VpT columns
    const int bb = row0 >> 11;
    const int sbase = (row0 & 2047) + wm*64;
    #pragma unroll
    for (int nt = 0; nt < 4; ++nt) {
      int c = col0 + wn*64 + nt*16 + l16;
      float bv = Bv[c];
      bf16* col = VpT + (size_t)((bb << 10) + c) * SEQ;
      #pragma unroll
      for (int mt = 0; mt < 4; ++mt) {
        int s = sbase + mt*16 + quad*4;
        union { uint2 u; bf16 h[4]; } pk;
        #pragma unroll
        for (int j = 0; j < 4; ++j) pk.h[j] = __float2bfloat16(acc[mt][nt][j] + bv);
        *(uint2*)(col + s) = pk.u;
      }
    }
  }
}

// ---------------------------------------------------------------------------
// PATH A: output projection, BK=64, 128x64 tile, swapped mfma ->
// float4 16B epilogue stores to fp32 d_out.
// ---------------------------------------------------------------------------
__global__ __launch_bounds__(256) void gemm_out_dma(
    const bf16* __restrict__ A, const bf16* __restrict__ W,
    const float* __restrict__ Bv, float* __restrict__ C)
{
  __shared__ __align__(16) bf16 As[8*128*8];   // 16 KB
  __shared__ __align__(16) bf16 Ws[8*64*8];    // 8 KB
  const int K = D_MODEL, N = D_MODEL;
  const int tid  = threadIdx.x;
  const int lane = tid & 63, wave = tid >> 6;
  const int wm   = wave >> 1, wn = wave & 1;
  const int quad = lane >> 4, l16 = lane & 15;
  const int row0 = blockIdx.y * 128, col0 = blockIdx.x * 64;

  const f32x4 zero = {0.f, 0.f, 0.f, 0.f};
  f32x4 acc[4][2];
  #pragma unroll
  for (int i = 0; i < 4; ++i)
    #pragma unroll
    for (int j = 0; j < 2; ++j) acc[i][j] = zero;

  for (int k0 = 0; k0 < K; k0 += 64) {
    __syncthreads();
    #pragma unroll
    for (int t = 0; t < 4; ++t) {
      int s = t*256 + tid;
      int g = s >> 7, r = s & 127;
      lds_dma16(A + (size_t)(row0 + r)*K + k0 + g*8, &As[s*8]);
    }
    #pragma unroll
    for (int t = 0; t < 2; ++t) {
      int s = t*256 + tid;
      int g = s >> 6, r = s & 63;
      lds_dma16(W + (size_t)(col0 + r)*K + k0 + g*8, &Ws[s*8]);
    }
    __syncthreads();
    #pragma unroll
    for (int ks = 0; ks < 2; ++ks) {
      bf16x8 af[4], wf[2];
      #pragma unroll
      for (int mt = 0; mt < 4; ++mt)
        af[mt] = *(const bf16x8*)&As[((ks*4 + quad)*128 + wm*64 + mt*16 + l16)*8];
      #pragma unroll
      for (int nt = 0; nt < 2; ++nt)
        wf[nt] = *(const bf16x8*)&Ws[((ks*4 + quad)*64 + wn*32 + nt*16 + l16)*8];
      #pragma unroll
      for (int mt = 0; mt < 4; ++mt)
        #pragma unroll
        for (int nt = 0; nt < 2; ++nt)
          acc[mt][nt] = __builtin_amdgcn_mfma_f32_16x16x32_bf16(wf[nt], af[mt], acc[mt][nt], 0, 0, 0);
    }
  }

  #pragma unroll
  for (int mt = 0; mt < 4; ++mt) {
    int r = row0 + wm*64 + mt*16 + l16;
    #pragma unroll
    for (int nt = 0; nt < 2; ++nt) {
      int c0 = col0 + wn*32 + nt*16 + quad*4;
      float4 b4 = *(const float4*)(Bv + c0);
      float4 o;
      o.x = acc[mt][nt][0] + b4.x; o.y = acc[mt][nt][1] + b4.y;
      o.z = acc[mt][nt][2] + b4.z; o.w = acc[mt][nt][3] + b4.w;
      *(float4*)&C[(size_t)r*N + c0] = o;
    }
  }
}

// ---------------------------------------------------------------------------
// PATH B fallback (small ws): fused fp32->bf16 staging, BK=32, same
// swapped epilogues.
// ---------------------------------------------------------------------------
__global__ __launch_bounds__(256) void gemm3_fused(
    const float* A0, const float* A1, const float* A2,
    const float* W0, const float* W1, const float* W2,
    const float* B0, const float* B1, const float* B2,
    bf16* C0, bf16* C1, bf16* VpT)
{
  __shared__ __align__(16) bf16 As[4*128*8];
  __shared__ __align__(16) bf16 Ws[4*128*8];
  const int z = blockIdx.z;
  const float* A = (z == 0) ? A0 : (z == 1) ? A1 : A2;
  const float* W = (z == 0) ? W0 : (z == 1) ? W1 : W2;
  const float* Bv = (z == 0) ? B0 : (z == 1) ? B1 : B2;
  const bool swapped = (z < 2);
  const int K = D_MODEL, N = D_MODEL;
  const int tid  = threadIdx.x;
  const int lane = tid & 63, wave = tid >> 6;
  const int wm   = wave >> 1, wn = wave & 1;
  const int quad = lane >> 4, l16 = lane & 15;
  const int row0 = blockIdx.y * 128, col0 = blockIdx.x * 128;

  const f32x4 zero = {0.f, 0.f, 0.f, 0.f};
  f32x4 acc[4][4];
  #pragma unroll
  for (int i = 0; i < 4; ++i)
    #pragma unroll
    for (int j = 0; j < 4; ++j) acc[i][j] = zero;

  for (int k0 = 0; k0 < K; k0 += 32) {
    __syncthreads();
    #pragma unroll
    for (int t = 0; t < 2; ++t) {
      int s = t*256 + tid;
      int g = s >> 7, r = s & 127;
      const float* Af = A + (size_t)(row0 + r)*K + k0 + g*8;
      *(uint4*)&As[s*8] = pack8_f32(((const float4*)Af)[0], ((const float4*)Af)[1]);
      const float* Wf = W + (size_t)(col0 + r)*K + k0 + g*8;
      *(uint4*)&Ws[s*8] = pack8_f32(((const float4*)Wf)[0], ((const float4*)Wf)[1]);
    }
    __syncthreads();
    bf16x8 af[4], wf[4];
    #pragma unroll
    for (int mt = 0; mt < 4; ++mt)
      af[mt] = *(const bf16x8*)&As[(quad*128 + wm*64 + mt*16 + l16)*8];
    #pragma unroll
    for (int nt = 0; nt < 4; ++nt)
      wf[nt] = *(const bf16x8*)&Ws[(quad*128 + wn*64 + nt*16 + l16)*8];
    if (swapped) {
      #pragma unroll
      for (int mt = 0; mt < 4; ++mt)
        #pragma unroll
        for (int nt = 0; nt < 4; ++nt)
          acc[mt][nt] = __builtin_amdgcn_mfma_f32_16x16x32_bf16(wf[nt], af[mt], acc[mt][nt], 0, 0, 0);
    } else {
      #pragma unroll
      for (int mt = 0; mt < 4; ++mt)
        #pragma unroll
        for (int nt = 0; nt < 4; ++nt)
          acc[mt][nt] = __builtin_amdgcn_mfma_f32_16x16x32_bf16(af[mt], wf[nt], acc[mt][nt], 0, 0, 0);
    }
  }

  if (swapped) {
    bf16* C = (z == 0) ? C0 : C1;
    const float scale = (z == 0) ? 0.125f*LOG2E : 1.0f;
    #pragma unroll
    for (int mt = 0; mt < 4; ++mt) {
      int r = row0 + wm*64 + mt*16 + l16;
      #pragma unroll
      for (int nt = 0; nt < 4; ++nt) {
        int c0 = col0 + wn*64 + nt*16 + quad*4;
        float4 b4 = *(const float4*)(Bv + c0);
        union { uint2 u; bf16 h[4]; } pk;
        pk.h[0] = __float2bfloat16((acc[mt][nt][0] + b4.x) * scale);
        pk.h[1] = __float2bfloat16((acc[mt][nt][1] + b4.y) * scale);
        pk.h[2] = __float2bfloat16((acc[mt][nt][2] + b4.z) * scale);
        pk.h[3] = __float2bfloat16((acc[mt][nt][3] + b4.w) * scale);
        *(uint2*)&C[(size_t)r*N + c0] = pk.u;
      }
    }
  } else {
    const int bb = row0 >> 11;
    const int sbase = (row0 & 2047) + wm*64;
    #pragma unroll
    for (int nt = 0; nt < 4; ++nt) {
      int c = col0 + wn*64 + nt*16 + l16;
      float bv = Bv[c];
      bf16* col = VpT + (size_t)((bb << 10) + c) * SEQ;
      #pragma unroll
      for (int mt = 0; mt < 4; ++mt) {
        int s = sbase + mt*16 + quad*4;
        union { uint2 u; bf16 h[4]; } pk;
        #pragma unroll
        for (int j = 0; j < 4; ++j) pk.h[j] = __float2bfloat16(acc[mt][nt][j] + bv);
        *(uint2*)(col + s) = pk.u;
      }
    }
  }
}

__global__ __launch_bounds__(256) void gemm_out_fused(
    const bf16* __restrict__ A, const float* __restrict__ W,
    const float* __restrict__ Bv, float* __restrict__ C)
{
  __shared__ __align__(16) bf16 As[4*128*8];
  __shared__ __align__(16) bf16 Ws[4*64*8];
  const int K = D_MODEL, N = D_MODEL;
  const int tid  = threadIdx.x;
  const int lane = tid & 63, wave = tid >> 6;
  const int wm   = wave >> 1, wn = wave & 1;
  const int quad = lane >> 4, l16 = lane & 15;
  const int row0 = blockIdx.y * 128, col0 = blockIdx.x * 64;

  const f32x4 zero = {0.f, 0.f, 0.f, 0.f};
  f32x4 acc[4][2];
  #pragma unroll
  for (int i = 0; i < 4; ++i)
    #pragma unroll
    for (int j = 0; j < 2; ++j) acc[i][j] = zero;

  for (int k0 = 0; k0 < K; k0 += 32) {
    __syncthreads();
    #pragma unroll
    for (int t = 0; t < 2; ++t) {
      int s = t*256 + tid;
      int g = s >> 7, r = s & 127;
      *(uint4*)&As[s*8] = *(const uint4*)(A + (size_t)(row0 + r)*K + k0 + g*8);
    }
    {
      int g = tid >> 6, r = tid & 63;
      const float* Wf = W + (size_t)(col0 + r)*K + k0 + g*8;
      *(uint4*)&Ws[tid*8] = pack8_f32(((const float4*)Wf)[0], ((const float4*)Wf)[1]);
    }
    __syncthreads();
    bf16x8 af[4], wf[2];
    #pragma unroll
    for (int mt = 0; mt < 4; ++mt)
      af[mt] = *(const bf16x8*)&As[(quad*128 + wm*64 + mt*16 + l16)*8];
    #pragma unroll
    for (int nt = 0; nt < 2; ++nt)
      wf[nt] = *(const bf16x8*)&Ws[(quad*64 + wn*32 + nt*16 + l16)*8];
    #pragma unroll
    for (int mt = 0; mt < 4; ++mt)
      #pragma unroll
      for (int nt = 0; nt < 2; ++nt)
        acc[mt][nt] = __builtin_amdgcn_mfma_f32_16x16x32_bf16(wf[nt], af[mt], acc[mt][nt], 0, 0, 0);
  }
  #pragma unroll
  for (int mt = 0; mt < 4; ++mt) {
    int r = row0 + wm*64 + mt*16 + l16;
    #pragma unroll
    for (int nt = 0; nt < 2; ++nt) {
      int c0 = col0 + wn*32 + nt*16 + quad*4;
      float4 b4 = *(const float4*)(Bv + c0);
      float4 o;
      o.x = acc[mt][nt][0] + b4.x; o.y = acc[mt][nt][1] + b4.y;
      o.z = acc[mt][nt][2] + b4.z; o.w = acc[mt][nt][3] + b4.w;
      *(float4*)&C[(size_t)r*N + c0] = o;
    }
  }
}

// ---------------------------------------------------------------------------
// Flash attention: 512 threads (8 waves x 16 q-rows), q-tile 128, K-tile 128.
// S^T = K Q^T, O^T = V^T P^T, log2-domain softmax. V-tile prefetched into
// registers one tile ahead (global load latency hidden behind compute).
// ---------------------------------------------------------------------------
__global__ __launch_bounds__(512) void attn_fused(
    const bf16* __restrict__ Qp, const bf16* __restrict__ Kp,
    const bf16* __restrict__ VpT, bf16* __restrict__ Ao)
{
  __shared__ __align__(16) bf16 UN[128*128];    // 32 KB: Qs staging then Ps
  __shared__ __align__(16) bf16 Ks[8*128*8];    // 16 KB
  __shared__ __align__(16) bf16 Vt[64*16*8];    // 16 KB  V^T swizzled

  const int tid  = threadIdx.x;
  const int lane = tid & 63, wave = tid >> 6;
  const int quad = lane >> 4, l16 = lane & 15;
  const int qt = blockIdx.x, h = blockIdx.y, b = blockIdx.z;
  const int q0 = qt * 128;
  const bf16* Qb = Qp + ((size_t)b*SEQ + q0)*D_MODEL + h*DHEAD;
  const bf16* Kb = Kp + (size_t)b*SEQ*D_MODEL + h*DHEAD;
  const bf16* Vg = VpT + (size_t)((b << 10) + h*DHEAD) * SEQ;

  // stage Q once via DMA into UN's first 16 KB
  #pragma unroll
  for (int t = 0; t < 2; ++t) {
    int s = t*512 + tid;
    int g = s >> 7, r = s & 127;
    lds_dma16(Qb + (size_t)r*D_MODEL + g*8, &UN[s*8]);
  }
  __syncthreads();

  const int wq0 = wave * 16;
  const int q   = wq0 + l16;
  bf16x8 qa[2];
  #pragma unroll
  for (int ks = 0; ks < 2; ++ks)
    qa[ks] = *(const bf16x8*)&UN[((ks*4 + quad)*128 + q)*8];
  bf16* Ps = UN;
  const int swz = (l16 & 7) << 1;

  // V prefetch slots: thread handles chunks c0 = tid, c1 = 512+tid
  const int vn0 = tid >> 4,        vgk0 = tid & 15;
  const int vn1 = (512+tid) >> 4,  vgk1 = (512+tid) & 15;
  const int vsw0 = (vgk0 + vn0 + (vn0 >> 3)) & 15;
  const int vsw1 = (vgk1 + vn1 + (vn1 >> 3)) & 15;
  uint4 vreg0 = *(const uint4*)(Vg + (size_t)vn0*SEQ + vgk0*8);
  uint4 vreg1 = *(const uint4*)(Vg + (size_t)vn1*SEQ + vgk1*8);

  const f32x4 zero = {0.f, 0.f, 0.f, 0.f};
  f32x4 acc_o[4];
  #pragma unroll
  for (int dt = 0; dt < 4; ++dt) acc_o[dt] = zero;
  float m_s = -1e30f, l_s = 0.f;

  for (int kt = 0; kt < SEQ/128; ++kt) {
    __syncthreads();                 // waves done with prev Ks/Vt (+ Q reads)
    // K tile via DMA
    #pragma unroll
    for (int t = 0; t < 2; ++t) {
      int s = t*512 + tid;
      int g = s >> 7, kk = s & 127;
      lds_dma16(Kb + (size_t)(kt*128 + kk)*D_MODEL + g*8, &Ks[s*8]);
    }
    // V^T tile: write prefetched regs, then prefetch next tile
    *(uint4*)&Vt[(vn0*16 + vsw0)*8] = vreg0;
    *(uint4*)&Vt[(vn1*16 + vsw1)*8] = vreg1;
    {
      int ktn = (kt + 1 < SEQ/128) ? kt + 1 : kt;
      vreg0 = *(const uint4*)(Vg + (size_t)vn0*SEQ + ktn*128 + vgk0*8);
      vreg1 = *(const uint4*)(Vg + (size_t)vn1*SEQ + ktn*128 + vgk1*8);
    }
    __syncthreads();

    // ---- S^T = K Q^T : D[key = kt2*16+quad*4+j][q = l16] ----
    f32x4 sc[8];
    #pragma unroll
    for (int kt2 = 0; kt2 < 8; ++kt2) sc[kt2] = zero;
    #pragma unroll
    for (int ks = 0; ks < 2; ++ks) {
      bf16x8 kf[8];
      #pragma unroll
      for (int kt2 = 0; kt2 < 8; ++kt2)
        kf[kt2] = *(const bf16x8*)&Ks[((ks*4 + quad)*128 + kt2*16 + l16)*8];
      #pragma unroll
      for (int kt2 = 0; kt2 < 8; ++kt2)
        sc[kt2] = __builtin_amdgcn_mfma_f32_16x16x32_bf16(kf[kt2], qa[ks], sc[kt2], 0, 0, 0);
    }

    // ---- online softmax (log2 domain) ----
    float vmax = -1e30f;
    #pragma unroll
    for (int kt2 = 0; kt2 < 8; ++kt2) {
      f32x4 s4 = sc[kt2];
      vmax = fmaxf(vmax, fmaxf(fmaxf(s4[0], s4[1]), fmaxf(s4[2], s4[3])));
    }
    vmax = fmaxf(vmax, __shfl_xor(vmax, 16));
    vmax = fmaxf(vmax, __shfl_xor(vmax, 32));
    float mnew  = fmaxf(m_s, vmax);
    float alpha = __builtin_amdgcn_exp2f(m_s - mnew);
    float rs = 0.f;
    #pragma unroll
    for (int kt2 = 0; kt2 < 8; ++kt2) {
      float p0 = __builtin_amdgcn_exp2f(sc[kt2][0] - mnew);
      float p1 = __builtin_amdgcn_exp2f(sc[kt2][1] - mnew);
      float p2 = __builtin_amdgcn_exp2f(sc[kt2][2] - mnew);
      float p3 = __builtin_amdgcn_exp2f(sc[kt2][3] - mnew);
      rs += (p0 + p1) + (p2 + p3);
      union { uint2 u; bf16 hh[4]; } pk;
      pk.hh[0] = __float2bfloat16(p0); pk.hh[1] = __float2bfloat16(p1);
      pk.hh[2] = __float2bfloat16(p2); pk.hh[3] = __float2bfloat16(p3);
      int phys = (kt2*4 + quad) ^ swz;
      *(uint2*)&Ps[q*128 + phys*4] = pk.u;
    }
    rs += __shfl_xor(rs, 16);
    rs += __shfl_xor(rs, 32);
    l_s = l_s*alpha + rs;
    m_s = mnew;
    #pragma unroll
    for (int dt = 0; dt < 4; ++dt) acc_o[dt] = acc_o[dt] * alpha;
    // no barrier: Ps rows are wave-private; lgkmcnt orders write->read

    // ---- O^T += V^T P^T ----
    #pragma unroll
    for (int ks2 = 0; ks2 < 4; ++ks2) {
      bf16x8 vf[4], pa;
      #pragma unroll
      for (int dt = 0; dt < 4; ++dt) {
        int n = dt*16 + l16;
        int sw = (ks2*4 + quad + n + (n >> 3)) & 15;
        vf[dt] = *(const bf16x8*)&Vt[(n*16 + sw)*8];
      }
      int phys = (ks2*8 + quad*2) ^ swz;
      pa = *(const bf16x8*)&Ps[q*128 + phys*4];
      #pragma unroll
      for (int dt = 0; dt < 4; ++dt)
        acc_o[dt] = __builtin_amdgcn_mfma_f32_16x16x32_bf16(vf[dt], pa, acc_o[dt], 0, 0, 0);
    }
  }

  bf16* Ob = Ao + ((size_t)b*SEQ + q0)*D_MODEL + h*DHEAD;
  float inv = 1.f / l_s;
  #pragma unroll
  for (int dt = 0; dt < 4; ++dt) {
    union { uint2 u; bf16 hh[4]; } pk;
    #pragma unroll
    for (int j = 0; j < 4; ++j) pk.hh[j] = __float2bfloat16(acc_o[dt][j] * inv);
    *(uint2*)(Ob + (size_t)q*D_MODEL + dt*16 + quad*4) = pk.u;
  }
}

// ---------------------------------------------------------------------------
extern "C" void kernel_launch(void* const* d_in, const int* in_sizes, int n_in,
                              void* d_out, int out_size, void* d_ws, size_t ws_size,
                              hipStream_t stream) {
  const float* q   = (const float*)d_in[0];
  const float* k   = (const float*)d_in[1];
  const float* v   = (const float*)d_in[2];
  const float* w_q = (const float*)d_in[3];
  const float* b_q = (const float*)d_in[4];
  const float* w_k = (const float*)d_in[5];
  const float* b_k = (const float*)d_in[6];
  const float* w_v = (const float*)d_in[7];
  const float* b_v = (const float*)d_in[8];
  const float* w_o = (const float*)d_in[9];
  const float* b_o = (const float*)d_in[10];

  const size_t nbuf = (size_t)MROWS * D_MODEL;
  const size_t wbuf = (size_t)D_MODEL * D_MODEL;
  bf16* Kp  = (bf16*)d_out;                       // d_out (fp32,16.8MB) scratch
  bf16* VpT = Kp + nbuf;

  const size_t needA = 256 + (3*nbuf + 4*wbuf + nbuf) * 2;  // ~41.9 MB
  if (ws_size >= needA) {
    bf16* qc  = (bf16*)((char*)d_ws + 256);
    bf16* kc  = qc  + nbuf;
    bf16* vc  = kc  + nbuf;
    bf16* wqc = vc  + nbuf;
    bf16* wkc = wqc + wbuf;
    bf16* wvc = wkc + wbuf;
    bf16* woc = wvc + wbuf;
    bf16* Qp  = woc + wbuf;
    bf16* Ao  = Qp;                   // alias: block-local slices only

    convert7<<<dim3(512,7), 256, 0, stream>>>(q, k, v, w_q, w_k, w_v, w_o,
                                              qc, kc, vc, wqc, wkc, wvc, woc);
    gemm3_dma<<<dim3(8,32,3), 256, 0, stream>>>(qc, kc, vc, wqc, wkc, wvc,
                                                b_q, b_k, b_v, Qp, Kp, VpT);
    attn_fused<<<dim3(16,16,2), 512, 0, stream>>>(Qp, Kp, VpT, Ao);
    gemm_out_dma<<<dim3(16,32), 256, 0, stream>>>(Ao, woc, b_o, (float*)d_out);
  } else {
    bf16* Qp = (bf16*)((char*)d_ws + 256);
    bf16* Ao = Qp;
    gemm3_fused<<<dim3(8,32,3), 256, 0, stream>>>(q, k, v, w_q, w_k, w_v,
                                                  b_q, b_k, b_v, Qp, Kp, VpT);
    attn_fused<<<dim3(16,16,2), 512, 0, stream>>>(Qp, Kp, VpT, Ao);
    gemm_out_fused<<<dim3(16,32), 256, 0, stream>>>(Ao, w_o, b_o, (float*)d_out);
  }
}